// Round 5
// baseline (470.997 us; speedup 1.0000x reference)
//
#include <hip/hip_runtime.h>
#include <stdint.h>

// ---------------------------------------------------------------------------
// B=32, C=4, S=256, L=256, Din=Dout=256
// Pipeline:
//   K1 corr_gemm:   corr[b] = fm[b] @ fm[b]^T          (f32 GEMM, 64x64 tiles)
//   K2 decide_norm: adj[b,s,:] = rownorm(gumbel-hard(MLP(corr[b,s,:])))
//                   one wave per row; f32 fast path, |margin|>=2e-3 guard,
//                   exact-f64 fallback (global dot + f64 MLP + f64 gumbel)
//   K3 gemm:        X[b,c] = adj[b] @ F[b,c]
//   K4 gemm:        out    = X @ Wl + bl
// threefry partitionable (jax key 42): bits(i) = o0^o1 of tf2x32((0,42),(0,i))
// ---------------------------------------------------------------------------

__device__ __forceinline__ void threefry2x32(uint32_t x0, uint32_t x1,
                                             uint32_t& o0, uint32_t& o1) {
  const uint32_t ks0 = 0u;
  const uint32_t ks1 = 42u;
  const uint32_t ks2 = 0x1BD11BDAu ^ ks0 ^ ks1;
  const uint32_t ks[3] = {ks0, ks1, ks2};
  const uint32_t rot[2][4] = {{13u, 15u, 26u, 6u}, {17u, 29u, 16u, 24u}};
  x0 += ks0;
  x1 += ks1;
#pragma unroll
  for (int i = 0; i < 5; ++i) {
#pragma unroll
    for (int j = 0; j < 4; ++j) {
      const uint32_t r = rot[i & 1][j];
      x0 += x1;
      x1 = (x1 << r) | (x1 >> (32u - r));
      x1 ^= x0;
    }
    x0 += ks[(i + 1) % 3];
    x1 += ks[(i + 2) % 3] + (uint32_t)(i + 1);
  }
  o0 = x0;
  o1 = x1;
}

__device__ __forceinline__ float uniform_at(uint32_t j) {
  uint32_t o0, o1;
  threefry2x32(0u, j, o0, o1);
  const uint32_t bits = o0 ^ o1;
  uint32_t fb = (bits >> 9) | 0x3F800000u;
  float frac = __uint_as_float(fb) - 1.0f;
  return fmaxf(frac + 1e-10f, 1e-10f);
}

__device__ __forceinline__ double gumbel64_at(uint32_t j) {
  double t = -log((double)uniform_at(j));
  return -log(t);
}

__device__ __forceinline__ float gumbel32_at(uint32_t j) {
  float t = -logf(uniform_at(j));
  return -logf(t);
}

__device__ __forceinline__ double gelu_d(double x) {
  return 0.5 * x * (1.0 + erf(x * 0.70710678118654752440));
}

__device__ __forceinline__ float gelu_f(float x) {
  return 0.5f * x * (1.0f + erff(x * 0.70710678f));
}

// f32 MLP 1->16->8->2, returns l0-l1
__device__ __forceinline__ float mlp32(float corr, const float* __restrict__ W1,
                                       const float* __restrict__ b1,
                                       const float* __restrict__ W2,
                                       const float* __restrict__ b2,
                                       const float* __restrict__ W3,
                                       const float* __restrict__ b3) {
  float h1[16];
#pragma unroll
  for (int u = 0; u < 16; ++u) h1[u] = gelu_f(fmaf(corr, W1[u], b1[u]));
  float h2[8];
#pragma unroll
  for (int v = 0; v < 8; ++v) {
    float x = b2[v];
#pragma unroll
    for (int u = 0; u < 16; ++u) x = fmaf(h1[u], W2[u * 8 + v], x);
    h2[v] = gelu_f(x);
  }
  float l0 = b3[0], l1 = b3[1];
#pragma unroll
  for (int v = 0; v < 8; ++v) {
    l0 = fmaf(h2[v], W3[v * 2 + 0], l0);
    l1 = fmaf(h2[v], W3[v * 2 + 1], l1);
  }
  return l0 - l1;
}

// exact f64 dot over 256 f32 elements read from GLOBAL (fallback only)
__device__ __noinline__ double dot64_global(const float* __restrict__ Srow,
                                            const float* __restrict__ Trow) {
  double a0 = 0.0, a1 = 0.0, a2 = 0.0, a3 = 0.0;
  for (int k = 0; k < 256; k += 4) {
    a0 += (double)Srow[k + 0] * (double)Trow[k + 0];
    a1 += (double)Srow[k + 1] * (double)Trow[k + 1];
    a2 += (double)Srow[k + 2] * (double)Trow[k + 2];
    a3 += (double)Srow[k + 3] * (double)Trow[k + 3];
  }
  return (a0 + a2) + (a1 + a3);
}

// exact f64 MLP (identical op order to the validated round-2 path)
__device__ __noinline__ void mlp64(double acc, const float* __restrict__ W1,
                                   const float* __restrict__ b1,
                                   const float* __restrict__ W2,
                                   const float* __restrict__ b2,
                                   const float* __restrict__ W3,
                                   const float* __restrict__ b3, double& l0,
                                   double& l1) {
  double h1[16];
#pragma unroll
  for (int i = 0; i < 16; ++i)
    h1[i] = gelu_d(acc * (double)W1[i] + (double)b1[i]);
  double h2[8];
#pragma unroll
  for (int j = 0; j < 8; ++j) {
    double v = (double)b2[j];
#pragma unroll
    for (int i = 0; i < 16; ++i) v += h1[i] * (double)W2[i * 8 + j];
    h2[j] = gelu_d(v);
  }
  l0 = (double)b3[0];
  l1 = (double)b3[1];
#pragma unroll
  for (int j = 0; j < 8; ++j) {
    l0 += h2[j] * (double)W3[j * 2 + 0];
    l1 += h2[j] * (double)W3[j * 2 + 1];
  }
}

// ---------------------------------------------------------------------------
// K1: corr[b] = fm[b] @ fm[b]^T.  grid (4,4,32), 256 threads.
// 64x64 tile, BK=32, 4x4 micro-tile. LDS 17.4 KB -> 8 blocks/CU.
// ---------------------------------------------------------------------------
__global__ __launch_bounds__(256) void corr_gemm_kernel(
    const float* __restrict__ fm, float* __restrict__ corr) {
  const int b = blockIdx.z;
  const int row0 = blockIdx.y * 64;
  const int col0 = blockIdx.x * 64;
  const float* base = fm + (size_t)b * 65536;

  __shared__ float As[32][68];  // As[k][m], pitch 68 keeps b128 reads aligned
  __shared__ float Bs[32][68];  // Bs[k][n]

  const int tid = threadIdx.x;
  const int tx = tid & 15;   // 0..15 -> col group
  const int ty = tid >> 4;   // 0..15 -> row group
  const int m = tid >> 2;        // 0..63 staging row
  const int c = (tid & 3) * 8;   // 0,8,16,24 staging k-offset

  float acc[4][4];
#pragma unroll
  for (int i = 0; i < 4; ++i)
#pragma unroll
    for (int j = 0; j < 4; ++j) acc[i][j] = 0.0f;

  for (int k0 = 0; k0 < 256; k0 += 32) {
    float4 v0 = *(const float4*)(base + (size_t)(row0 + m) * 256 + k0 + c);
    float4 v1 = *(const float4*)(base + (size_t)(row0 + m) * 256 + k0 + c + 4);
    float4 w0 = *(const float4*)(base + (size_t)(col0 + m) * 256 + k0 + c);
    float4 w1 = *(const float4*)(base + (size_t)(col0 + m) * 256 + k0 + c + 4);
    __syncthreads();  // previous iteration's reads done before overwrite
    As[c + 0][m] = v0.x; As[c + 1][m] = v0.y;
    As[c + 2][m] = v0.z; As[c + 3][m] = v0.w;
    As[c + 4][m] = v1.x; As[c + 5][m] = v1.y;
    As[c + 6][m] = v1.z; As[c + 7][m] = v1.w;
    Bs[c + 0][m] = w0.x; Bs[c + 1][m] = w0.y;
    Bs[c + 2][m] = w0.z; Bs[c + 3][m] = w0.w;
    Bs[c + 4][m] = w1.x; Bs[c + 5][m] = w1.y;
    Bs[c + 6][m] = w1.z; Bs[c + 7][m] = w1.w;
    __syncthreads();

#pragma unroll
    for (int kk = 0; kk < 32; ++kk) {
      float a[4], bv[4];
      *(float4*)a = *(const float4*)(&As[kk][ty * 4]);
      *(float4*)bv = *(const float4*)(&Bs[kk][tx * 4]);
#pragma unroll
      for (int i = 0; i < 4; ++i)
#pragma unroll
        for (int j = 0; j < 4; ++j) acc[i][j] = fmaf(a[i], bv[j], acc[i][j]);
    }
  }

  float* Cb = corr + (size_t)b * 65536;
#pragma unroll
  for (int i = 0; i < 4; ++i) {
    const int row = row0 + ty * 4 + i;
    float4 o = {acc[i][0], acc[i][1], acc[i][2], acc[i][3]};
    *(float4*)(Cb + (size_t)row * 256 + col0 + tx * 4) = o;
  }
}

// ---------------------------------------------------------------------------
// K2: decisions + fused row-normalize. One wave per (b,s) row.
// grid 2048 blocks x 256 threads (4 waves/block = 4 rows/block).
// ---------------------------------------------------------------------------
__global__ __launch_bounds__(256) void decide_norm_kernel(
    const float* __restrict__ corr, const float* __restrict__ fm,
    const float* __restrict__ W1, const float* __restrict__ b1,
    const float* __restrict__ W2, const float* __restrict__ b2,
    const float* __restrict__ W3, const float* __restrict__ b3,
    float* __restrict__ adj) {
  const int lane = threadIdx.x & 63;
  const int w = threadIdx.x >> 6;
  const int row = blockIdx.x * 4 + w;  // 0..8191
  const int b = row >> 8;
  const int s = row & 255;

  const float4 cv = ((const float4*)(corr + (size_t)row * 256))[lane];
  const float cf4[4] = {cv.x, cv.y, cv.z, cv.w};

  float a[4];
  float csum = 0.0f;
#pragma unroll
  for (int e = 0; e < 4; ++e) {
    const int t = lane * 4 + e;
    const float dphi = mlp32(cf4[e], W1, b1, W2, b2, W3, b3);
    const uint32_t base =
        ((uint32_t)b << 16) | ((uint32_t)s << 8) | (uint32_t)t;
    const float g0 = gumbel32_at(2u * base);
    const float g1 = gumbel32_at(2u * base + 1u);
    const float d = dphi - (g1 - g0);
    float av;
    if (fabsf(d) >= 2e-3f) {
      av = (d >= 0.0f) ? 1.0f : 0.0f;
    } else {
      // exact f64 recompute: global dot + f64 MLP + f64 gumbel
      const float* Srow = fm + ((size_t)b * 256 + s) * 256;
      const float* Trow = fm + ((size_t)b * 256 + t) * 256;
      double l0e, l1e;
      mlp64(dot64_global(Srow, Trow), W1, b1, W2, b2, W3, b3, l0e, l1e);
      const double G0 = gumbel64_at(2u * base);
      const double G1 = gumbel64_at(2u * base + 1u);
      av = (l0e + G0 >= l1e + G1) ? 1.0f : 0.0f;
    }
    if (t == s) av = 1.0f;
    a[e] = av;
    csum += av;
  }

  // wave-wide sum (exact: integer-valued f32)
#pragma unroll
  for (int off = 32; off; off >>= 1) csum += __shfl_xor(csum, off);
  const float r = 1.0f / csum;

  float4 o = {a[0] * r, a[1] * r, a[2] * r, a[3] * r};
  ((float4*)(adj + (size_t)row * 256))[lane] = o;
}

// ---------------------------------------------------------------------------
// K3/K4: f32 GEMM, M=N=K=256 per batch z. BM=BN=128, BK=8, 256 thr.
// ---------------------------------------------------------------------------
__global__ __launch_bounds__(256) void gemm_kernel(
    const float* __restrict__ A, const float* __restrict__ B,
    const float* __restrict__ bias, float* __restrict__ C,
    int aDiv, int bShared) {
  const int z = blockIdx.z;
  const float* Ab = A + (size_t)(z / aDiv) * 65536;
  const float* Bb = bShared ? B : (B + (size_t)z * 65536);
  float* Cb = C + (size_t)z * 65536;

  const int row0 = blockIdx.y * 128;
  const int col0 = blockIdx.x * 128;

  __shared__ float As[8][132];
  __shared__ float Bs[8][132];

  const int tid = threadIdx.x;
  const int tx = tid & 15;
  const int ty = tid >> 4;

  float acc[2][2][4][4];
#pragma unroll
  for (int a = 0; a < 2; ++a)
#pragma unroll
    for (int bq = 0; bq < 2; ++bq)
#pragma unroll
      for (int i = 0; i < 4; ++i)
#pragma unroll
        for (int j = 0; j < 4; ++j) acc[a][bq][i][j] = 0.0f;

  for (int k0 = 0; k0 < 256; k0 += 8) {
    {
      int r = tid >> 1, c = (tid & 1) * 4;
      float4 v = *(const float4*)(Ab + (size_t)(row0 + r) * 256 + k0 + c);
      As[c + 0][r] = v.x;
      As[c + 1][r] = v.y;
      As[c + 2][r] = v.z;
      As[c + 3][r] = v.w;
    }
    {
      int r = tid >> 5, c = (tid & 31) * 4;
      *(float4*)(&Bs[r][c]) =
          *(const float4*)(Bb + (size_t)(k0 + r) * 256 + col0 + c);
    }
    __syncthreads();

#pragma unroll
    for (int kk = 0; kk < 8; ++kk) {
      float a0[4], a1[4], b0[4], b1[4];
      *(float4*)a0 = *(const float4*)(&As[kk][ty * 4]);
      *(float4*)a1 = *(const float4*)(&As[kk][ty * 4 + 64]);
      *(float4*)b0 = *(const float4*)(&Bs[kk][tx * 4]);
      *(float4*)b1 = *(const float4*)(&Bs[kk][tx * 4 + 64]);
#pragma unroll
      for (int i = 0; i < 4; ++i)
#pragma unroll
        for (int j = 0; j < 4; ++j) {
          acc[0][0][i][j] += a0[i] * b0[j];
          acc[0][1][i][j] += a0[i] * b1[j];
          acc[1][0][i][j] += a1[i] * b0[j];
          acc[1][1][i][j] += a1[i] * b1[j];
        }
    }
    __syncthreads();
  }

#pragma unroll
  for (int ih = 0; ih < 2; ++ih)
#pragma unroll
    for (int i = 0; i < 4; ++i) {
      const int row = row0 + ih * 64 + ty * 4 + i;
#pragma unroll
      for (int jh = 0; jh < 2; ++jh) {
        const int col = col0 + jh * 64 + tx * 4;
        float4 o;
        o.x = acc[ih][jh][i][0];
        o.y = acc[ih][jh][i][1];
        o.z = acc[ih][jh][i][2];
        o.w = acc[ih][jh][i][3];
        if (bias) {
          float4 bv = *(const float4*)(bias + col);
          o.x += bv.x; o.y += bv.y; o.z += bv.z; o.w += bv.w;
        }
        *(float4*)(Cb + (size_t)row * 256 + col) = o;
      }
    }
}

extern "C" void kernel_launch(void* const* d_in, const int* in_sizes, int n_in,
                              void* d_out, int out_size, void* d_ws,
                              size_t ws_size, hipStream_t stream) {
  const float* features = (const float*)d_in[0];
  const float* fm       = (const float*)d_in[1];
  const float* W1 = (const float*)d_in[2];
  const float* b1 = (const float*)d_in[3];
  const float* W2 = (const float*)d_in[4];
  const float* b2 = (const float*)d_in[5];
  const float* W3 = (const float*)d_in[6];
  const float* b3 = (const float*)d_in[7];
  const float* Wl = (const float*)d_in[8];
  const float* bl = (const float*)d_in[9];
  float* out = (float*)d_out;

  // ws layout (41.9 MB total):
  //   adj  @ 0        .. 8.4 MB
  //   corr @ 8.4 MB   .. 16.8 MB   (dead after decide_norm)
  //   X    @ 8.4 MB   .. 41.9 MB   (overwrites corr - safe)
  float* adj  = (float*)d_ws;
  float* corr = (float*)d_ws + (size_t)32 * 256 * 256;
  float* X    = (float*)d_ws + (size_t)32 * 256 * 256;

  corr_gemm_kernel<<<dim3(4, 4, 32), 256, 0, stream>>>(fm, corr);
  decide_norm_kernel<<<dim3(2048), 256, 0, stream>>>(corr, fm, W1, b1, W2, b2,
                                                     W3, b3, adj);
  // X[b,c] = adj[b] @ F[b,c]   (X overwrites corr; corr fully consumed)
  gemm_kernel<<<dim3(2, 2, 128), 256, 0, stream>>>(adj, features, nullptr, X,
                                                   4, 0);
  // out[b,c] = X[b,c] @ Wl + bl
  gemm_kernel<<<dim3(2, 2, 128), 256, 0, stream>>>(X, Wl, bl, out, 1, 1);
}

// Round 6
// 304.657 us; speedup vs baseline: 1.5460x; 1.5460x over previous
//
#include <hip/hip_runtime.h>
#include <stdint.h>

// ---------------------------------------------------------------------------
// B=32, C=4, S=256, L=256, Din=Dout=256
// Pipeline:
//   K1 corr_gemm64: corr[b] = fm[b] @ fm[b]^T, f64 accumulate, f64 store
//   K2 decide_norm: adj[b,s,:] = rownorm(gumbel-hard(MLP(corr[b,s,:])))
//                   f32 fast path, |margin|>=2e-3 guard, f64 fallback
//                   (mlp64 + gumbel64 from stored corr64 - NO dot recompute)
//   K3 gemm:        X[b,c] = adj[b] @ F[b,c]
//   K4 gemm:        out    = X @ Wl + bl
// threefry partitionable (jax key 42): bits(i) = o0^o1 of tf2x32((0,42),(0,i))
// ---------------------------------------------------------------------------

__device__ __forceinline__ void threefry2x32(uint32_t x0, uint32_t x1,
                                             uint32_t& o0, uint32_t& o1) {
  const uint32_t ks0 = 0u;
  const uint32_t ks1 = 42u;
  const uint32_t ks2 = 0x1BD11BDAu ^ ks0 ^ ks1;
  const uint32_t ks[3] = {ks0, ks1, ks2};
  const uint32_t rot[2][4] = {{13u, 15u, 26u, 6u}, {17u, 29u, 16u, 24u}};
  x0 += ks0;
  x1 += ks1;
#pragma unroll
  for (int i = 0; i < 5; ++i) {
#pragma unroll
    for (int j = 0; j < 4; ++j) {
      const uint32_t r = rot[i & 1][j];
      x0 += x1;
      x1 = (x1 << r) | (x1 >> (32u - r));
      x1 ^= x0;
    }
    x0 += ks[(i + 1) % 3];
    x1 += ks[(i + 2) % 3] + (uint32_t)(i + 1);
  }
  o0 = x0;
  o1 = x1;
}

__device__ __forceinline__ float uniform_at(uint32_t j) {
  uint32_t o0, o1;
  threefry2x32(0u, j, o0, o1);
  const uint32_t bits = o0 ^ o1;
  uint32_t fb = (bits >> 9) | 0x3F800000u;
  float frac = __uint_as_float(fb) - 1.0f;
  return fmaxf(frac + 1e-10f, 1e-10f);
}

__device__ __forceinline__ double gumbel64_at(uint32_t j) {
  double t = -log((double)uniform_at(j));
  return -log(t);
}

__device__ __forceinline__ float gumbel32_at(uint32_t j) {
  float t = -logf(uniform_at(j));
  return -logf(t);
}

__device__ __forceinline__ double gelu_d(double x) {
  return 0.5 * x * (1.0 + erf(x * 0.70710678118654752440));
}

__device__ __forceinline__ float gelu_f(float x) {
  return 0.5f * x * (1.0f + erff(x * 0.70710678f));
}

// f32 MLP 1->16->8->2, returns l0-l1
__device__ __forceinline__ float mlp32(float corr, const float* __restrict__ W1,
                                       const float* __restrict__ b1,
                                       const float* __restrict__ W2,
                                       const float* __restrict__ b2,
                                       const float* __restrict__ W3,
                                       const float* __restrict__ b3) {
  float h1[16];
#pragma unroll
  for (int u = 0; u < 16; ++u) h1[u] = gelu_f(fmaf(corr, W1[u], b1[u]));
  float h2[8];
#pragma unroll
  for (int v = 0; v < 8; ++v) {
    float x = b2[v];
#pragma unroll
    for (int u = 0; u < 16; ++u) x = fmaf(h1[u], W2[u * 8 + v], x);
    h2[v] = gelu_f(x);
  }
  float l0 = b3[0], l1 = b3[1];
#pragma unroll
  for (int v = 0; v < 8; ++v) {
    l0 = fmaf(h2[v], W3[v * 2 + 0], l0);
    l1 = fmaf(h2[v], W3[v * 2 + 1], l1);
  }
  return l0 - l1;
}

// exact f64 MLP (identical op order to the validated round-2 path)
__device__ __noinline__ void mlp64(double acc, const float* __restrict__ W1,
                                   const float* __restrict__ b1,
                                   const float* __restrict__ W2,
                                   const float* __restrict__ b2,
                                   const float* __restrict__ W3,
                                   const float* __restrict__ b3, double& l0,
                                   double& l1) {
  double h1[16];
#pragma unroll
  for (int i = 0; i < 16; ++i)
    h1[i] = gelu_d(acc * (double)W1[i] + (double)b1[i]);
  double h2[8];
#pragma unroll
  for (int j = 0; j < 8; ++j) {
    double v = (double)b2[j];
#pragma unroll
    for (int i = 0; i < 16; ++i) v += h1[i] * (double)W2[i * 8 + j];
    h2[j] = gelu_d(v);
  }
  l0 = (double)b3[0];
  l1 = (double)b3[1];
#pragma unroll
  for (int j = 0; j < 8; ++j) {
    l0 += h2[j] * (double)W3[j * 2 + 0];
    l1 += h2[j] * (double)W3[j * 2 + 1];
  }
}

// ---------------------------------------------------------------------------
// K1: corr[b] = fm[b] @ fm[b]^T with f64 accumulation, f64 output.
// grid (4,4,32), 256 threads. 64x64 tile, BK=32, 4x4 micro-tile.
// ---------------------------------------------------------------------------
__global__ __launch_bounds__(256) void corr_gemm64_kernel(
    const float* __restrict__ fm, double* __restrict__ corr) {
  const int b = blockIdx.z;
  const int row0 = blockIdx.y * 64;
  const int col0 = blockIdx.x * 64;
  const float* base = fm + (size_t)b * 65536;

  __shared__ float As[32][68];  // As[k][m]
  __shared__ float Bs[32][68];  // Bs[k][n]

  const int tid = threadIdx.x;
  const int tx = tid & 15;
  const int ty = tid >> 4;
  const int m = tid >> 2;
  const int c = (tid & 3) * 8;

  double acc[4][4];
#pragma unroll
  for (int i = 0; i < 4; ++i)
#pragma unroll
    for (int j = 0; j < 4; ++j) acc[i][j] = 0.0;

  for (int k0 = 0; k0 < 256; k0 += 32) {
    float4 v0 = *(const float4*)(base + (size_t)(row0 + m) * 256 + k0 + c);
    float4 v1 = *(const float4*)(base + (size_t)(row0 + m) * 256 + k0 + c + 4);
    float4 w0 = *(const float4*)(base + (size_t)(col0 + m) * 256 + k0 + c);
    float4 w1 = *(const float4*)(base + (size_t)(col0 + m) * 256 + k0 + c + 4);
    __syncthreads();
    As[c + 0][m] = v0.x; As[c + 1][m] = v0.y;
    As[c + 2][m] = v0.z; As[c + 3][m] = v0.w;
    As[c + 4][m] = v1.x; As[c + 5][m] = v1.y;
    As[c + 6][m] = v1.z; As[c + 7][m] = v1.w;
    Bs[c + 0][m] = w0.x; Bs[c + 1][m] = w0.y;
    Bs[c + 2][m] = w0.z; Bs[c + 3][m] = w0.w;
    Bs[c + 4][m] = w1.x; Bs[c + 5][m] = w1.y;
    Bs[c + 6][m] = w1.z; Bs[c + 7][m] = w1.w;
    __syncthreads();

#pragma unroll
    for (int kk = 0; kk < 32; ++kk) {
      float a[4], bv[4];
      *(float4*)a = *(const float4*)(&As[kk][ty * 4]);
      *(float4*)bv = *(const float4*)(&Bs[kk][tx * 4]);
      double ad[4], bd[4];
#pragma unroll
      for (int i = 0; i < 4; ++i) {
        ad[i] = (double)a[i];
        bd[i] = (double)bv[i];
      }
#pragma unroll
      for (int i = 0; i < 4; ++i)
#pragma unroll
        for (int j = 0; j < 4; ++j) acc[i][j] = fma(ad[i], bd[j], acc[i][j]);
    }
  }

  double* Cb = corr + (size_t)b * 65536;
#pragma unroll
  for (int i = 0; i < 4; ++i) {
    const int row = row0 + ty * 4 + i;
    double2 o0 = {acc[i][0], acc[i][1]};
    double2 o1 = {acc[i][2], acc[i][3]};
    *(double2*)(Cb + (size_t)row * 256 + col0 + tx * 4) = o0;
    *(double2*)(Cb + (size_t)row * 256 + col0 + tx * 4 + 2) = o1;
  }
}

// ---------------------------------------------------------------------------
// K2: decisions + fused row-normalize. One wave per (b,s) row.
// grid 2048 blocks x 256 threads (4 waves/block = 4 rows/block).
// Fallback is memory-free: f64 MLP + f64 gumbel on stored corr64.
// ---------------------------------------------------------------------------
__global__ __launch_bounds__(256) void decide_norm_kernel(
    const double* __restrict__ corr,
    const float* __restrict__ W1, const float* __restrict__ b1,
    const float* __restrict__ W2, const float* __restrict__ b2,
    const float* __restrict__ W3, const float* __restrict__ b3,
    float* __restrict__ adj) {
  const int lane = threadIdx.x & 63;
  const int w = threadIdx.x >> 6;
  const int row = blockIdx.x * 4 + w;  // 0..8191
  const int b = row >> 8;
  const int s = row & 255;

  const double2* cp = (const double2*)(corr + (size_t)row * 256);
  const double2 c01 = cp[lane * 2];
  const double2 c23 = cp[lane * 2 + 1];
  const double c4[4] = {c01.x, c01.y, c23.x, c23.y};

  float a[4];
  float csum = 0.0f;
#pragma unroll
  for (int e = 0; e < 4; ++e) {
    const int t = lane * 4 + e;
    if (t == s) {
      a[e] = 1.0f;
      csum += 1.0f;
      continue;
    }
    const double corr64 = c4[e];
    const float dphi = mlp32((float)corr64, W1, b1, W2, b2, W3, b3);
    const uint32_t base =
        ((uint32_t)b << 16) | ((uint32_t)s << 8) | (uint32_t)t;
    const float g0 = gumbel32_at(2u * base);
    const float g1 = gumbel32_at(2u * base + 1u);
    const float d = dphi - (g1 - g0);
    float av;
    if (fabsf(d) >= 2e-3f) {
      av = (d >= 0.0f) ? 1.0f : 0.0f;
    } else {
      double l0e, l1e;
      mlp64(corr64, W1, b1, W2, b2, W3, b3, l0e, l1e);
      const double G0 = gumbel64_at(2u * base);
      const double G1 = gumbel64_at(2u * base + 1u);
      av = (l0e + G0 >= l1e + G1) ? 1.0f : 0.0f;
    }
    a[e] = av;
    csum += av;
  }

  // wave-wide sum (exact: integer-valued f32)
#pragma unroll
  for (int off = 32; off; off >>= 1) csum += __shfl_xor(csum, off);
  const float r = 1.0f / csum;

  float4 o = {a[0] * r, a[1] * r, a[2] * r, a[3] * r};
  ((float4*)(adj + (size_t)row * 256))[lane] = o;
}

// ---------------------------------------------------------------------------
// K3/K4: f32 GEMM, M=N=K=256 per batch z. BM=BN=128, BK=8, 256 thr.
// ---------------------------------------------------------------------------
__global__ __launch_bounds__(256) void gemm_kernel(
    const float* __restrict__ A, const float* __restrict__ B,
    const float* __restrict__ bias, float* __restrict__ C,
    int aDiv, int bShared) {
  const int z = blockIdx.z;
  const float* Ab = A + (size_t)(z / aDiv) * 65536;
  const float* Bb = bShared ? B : (B + (size_t)z * 65536);
  float* Cb = C + (size_t)z * 65536;

  const int row0 = blockIdx.y * 128;
  const int col0 = blockIdx.x * 128;

  __shared__ float As[8][132];
  __shared__ float Bs[8][132];

  const int tid = threadIdx.x;
  const int tx = tid & 15;
  const int ty = tid >> 4;

  float acc[2][2][4][4];
#pragma unroll
  for (int a = 0; a < 2; ++a)
#pragma unroll
    for (int bq = 0; bq < 2; ++bq)
#pragma unroll
      for (int i = 0; i < 4; ++i)
#pragma unroll
        for (int j = 0; j < 4; ++j) acc[a][bq][i][j] = 0.0f;

  for (int k0 = 0; k0 < 256; k0 += 8) {
    {
      int r = tid >> 1, c = (tid & 1) * 4;
      float4 v = *(const float4*)(Ab + (size_t)(row0 + r) * 256 + k0 + c);
      As[c + 0][r] = v.x;
      As[c + 1][r] = v.y;
      As[c + 2][r] = v.z;
      As[c + 3][r] = v.w;
    }
    {
      int r = tid >> 5, c = (tid & 31) * 4;
      *(float4*)(&Bs[r][c]) =
          *(const float4*)(Bb + (size_t)(k0 + r) * 256 + col0 + c);
    }
    __syncthreads();

#pragma unroll
    for (int kk = 0; kk < 8; ++kk) {
      float a0[4], a1[4], b0[4], b1[4];
      *(float4*)a0 = *(const float4*)(&As[kk][ty * 4]);
      *(float4*)a1 = *(const float4*)(&As[kk][ty * 4 + 64]);
      *(float4*)b0 = *(const float4*)(&Bs[kk][tx * 4]);
      *(float4*)b1 = *(const float4*)(&Bs[kk][tx * 4 + 64]);
#pragma unroll
      for (int i = 0; i < 4; ++i)
#pragma unroll
        for (int j = 0; j < 4; ++j) {
          acc[0][0][i][j] += a0[i] * b0[j];
          acc[0][1][i][j] += a0[i] * b1[j];
          acc[1][0][i][j] += a1[i] * b0[j];
          acc[1][1][i][j] += a1[i] * b1[j];
        }
    }
    __syncthreads();
  }

#pragma unroll
  for (int ih = 0; ih < 2; ++ih)
#pragma unroll
    for (int i = 0; i < 4; ++i) {
      const int row = row0 + ih * 64 + ty * 4 + i;
#pragma unroll
      for (int jh = 0; jh < 2; ++jh) {
        const int col = col0 + jh * 64 + tx * 4;
        float4 o;
        o.x = acc[ih][jh][i][0];
        o.y = acc[ih][jh][i][1];
        o.z = acc[ih][jh][i][2];
        o.w = acc[ih][jh][i][3];
        if (bias) {
          float4 bv = *(const float4*)(bias + col);
          o.x += bv.x; o.y += bv.y; o.z += bv.z; o.w += bv.w;
        }
        *(float4*)(Cb + (size_t)row * 256 + col) = o;
      }
    }
}

extern "C" void kernel_launch(void* const* d_in, const int* in_sizes, int n_in,
                              void* d_out, int out_size, void* d_ws,
                              size_t ws_size, hipStream_t stream) {
  const float* features = (const float*)d_in[0];
  const float* fm       = (const float*)d_in[1];
  const float* W1 = (const float*)d_in[2];
  const float* b1 = (const float*)d_in[3];
  const float* W2 = (const float*)d_in[4];
  const float* b2 = (const float*)d_in[5];
  const float* W3 = (const float*)d_in[6];
  const float* b3 = (const float*)d_in[7];
  const float* Wl = (const float*)d_in[8];
  const float* bl = (const float*)d_in[9];
  float* out = (float*)d_out;

  // ws layout:
  //   adj    @ 0        .. 8.4 MB   (f32)
  //   corr64 @ 8.4 MB   .. 25.2 MB  (f64, dead after decide_norm)
  //   X      @ 8.4 MB   .. 41.9 MB  (f32, overwrites corr64 - safe)
  float* adj     = (float*)d_ws;
  double* corr64 = (double*)((char*)d_ws + (size_t)32 * 256 * 256 * 4);
  float* X       = (float*)d_ws + (size_t)32 * 256 * 256;

  corr_gemm64_kernel<<<dim3(4, 4, 32), 256, 0, stream>>>(fm, corr64);
  decide_norm_kernel<<<dim3(2048), 256, 0, stream>>>(corr64, W1, b1, W2, b2,
                                                     W3, b3, adj);
  // X[b,c] = adj[b] @ F[b,c]   (X overwrites corr64; corr64 fully consumed)
  gemm_kernel<<<dim3(2, 2, 128), 256, 0, stream>>>(adj, features, nullptr, X,
                                                   4, 0);
  // out[b,c] = X[b,c] @ Wl + bl
  gemm_kernel<<<dim3(2, 2, 128), 256, 0, stream>>>(X, Wl, bl, out, 1, 1);
}

// Round 7
// 199.109 us; speedup vs baseline: 2.3655x; 1.5301x over previous
//
#include <hip/hip_runtime.h>
#include <stdint.h>

// ---------------------------------------------------------------------------
// B=32, C=4, S=256, L=256, Din=Dout=256
// Pipeline:
//   K0 build_table: dphi table (131073 nodes over [-128,128], mlp32 nodes)
//   K1 corr_gemm64: corr[b] = fm[b] @ fm[b]^T, f64 accumulate, f64 store
//   K2 decide_norm: 1 elem/thread: lerp(dphi) + gumbel32 decision,
//                   |margin|>=4e-4 guard, validated mlp64+gumbel64 fallback;
//                   fused row-normalize (1 row per 256-thr block)
//   K3 gemm:        X[b,c] = adj[b] @ F[b,c]
//   K4 gemm:        out    = X @ Wl + bl
// threefry partitionable (jax key 42): bits(i) = o0^o1 of tf2x32((0,42),(0,i))
// ---------------------------------------------------------------------------

#define TBL_INTERVALS 131072
#define TBL_MIN -128.0f
#define TBL_SCALE 512.0f  // TBL_INTERVALS / 256

__device__ __forceinline__ void threefry2x32(uint32_t x0, uint32_t x1,
                                             uint32_t& o0, uint32_t& o1) {
  const uint32_t ks0 = 0u;
  const uint32_t ks1 = 42u;
  const uint32_t ks2 = 0x1BD11BDAu ^ ks0 ^ ks1;
  const uint32_t ks[3] = {ks0, ks1, ks2};
  const uint32_t rot[2][4] = {{13u, 15u, 26u, 6u}, {17u, 29u, 16u, 24u}};
  x0 += ks0;
  x1 += ks1;
#pragma unroll
  for (int i = 0; i < 5; ++i) {
#pragma unroll
    for (int j = 0; j < 4; ++j) {
      const uint32_t r = rot[i & 1][j];
      x0 += x1;
      x1 = (x1 << r) | (x1 >> (32u - r));
      x1 ^= x0;
    }
    x0 += ks[(i + 1) % 3];
    x1 += ks[(i + 2) % 3] + (uint32_t)(i + 1);
  }
  o0 = x0;
  o1 = x1;
}

__device__ __forceinline__ float uniform_at(uint32_t j) {
  uint32_t o0, o1;
  threefry2x32(0u, j, o0, o1);
  const uint32_t bits = o0 ^ o1;
  uint32_t fb = (bits >> 9) | 0x3F800000u;
  float frac = __uint_as_float(fb) - 1.0f;
  return fmaxf(frac + 1e-10f, 1e-10f);
}

__device__ __forceinline__ double gumbel64_at(uint32_t j) {
  double t = -log((double)uniform_at(j));
  return -log(t);
}

__device__ __forceinline__ float gumbel32_at(uint32_t j) {
  float t = -logf(uniform_at(j));
  return -logf(t);
}

__device__ __forceinline__ double gelu_d(double x) {
  return 0.5 * x * (1.0 + erf(x * 0.70710678118654752440));
}

__device__ __forceinline__ float gelu_f(float x) {
  return 0.5f * x * (1.0f + erff(x * 0.70710678f));
}

// f32 MLP 1->16->8->2, returns l0-l1
__device__ __forceinline__ float mlp32(float corr, const float* __restrict__ W1,
                                       const float* __restrict__ b1,
                                       const float* __restrict__ W2,
                                       const float* __restrict__ b2,
                                       const float* __restrict__ W3,
                                       const float* __restrict__ b3) {
  float h1[16];
#pragma unroll
  for (int u = 0; u < 16; ++u) h1[u] = gelu_f(fmaf(corr, W1[u], b1[u]));
  float h2[8];
#pragma unroll
  for (int v = 0; v < 8; ++v) {
    float x = b2[v];
#pragma unroll
    for (int u = 0; u < 16; ++u) x = fmaf(h1[u], W2[u * 8 + v], x);
    h2[v] = gelu_f(x);
  }
  float l0 = b3[0], l1 = b3[1];
#pragma unroll
  for (int v = 0; v < 8; ++v) {
    l0 = fmaf(h2[v], W3[v * 2 + 0], l0);
    l1 = fmaf(h2[v], W3[v * 2 + 1], l1);
  }
  return l0 - l1;
}

// exact f64 MLP (identical op order to the validated round-2 path)
__device__ __noinline__ void mlp64(double acc, const float* __restrict__ W1,
                                   const float* __restrict__ b1,
                                   const float* __restrict__ W2,
                                   const float* __restrict__ b2,
                                   const float* __restrict__ W3,
                                   const float* __restrict__ b3, double& l0,
                                   double& l1) {
  double h1[16];
#pragma unroll
  for (int i = 0; i < 16; ++i)
    h1[i] = gelu_d(acc * (double)W1[i] + (double)b1[i]);
  double h2[8];
#pragma unroll
  for (int j = 0; j < 8; ++j) {
    double v = (double)b2[j];
#pragma unroll
    for (int i = 0; i < 16; ++i) v += h1[i] * (double)W2[i * 8 + j];
    h2[j] = gelu_d(v);
  }
  l0 = (double)b3[0];
  l1 = (double)b3[1];
#pragma unroll
  for (int j = 0; j < 8; ++j) {
    l0 += h2[j] * (double)W3[j * 2 + 0];
    l1 += h2[j] * (double)W3[j * 2 + 1];
  }
}

// slow exact decision, used only inside the guard (rare)
__device__ __noinline__ float decide_exact(double corr64, uint32_t base,
                                           const float* __restrict__ W1,
                                           const float* __restrict__ b1,
                                           const float* __restrict__ W2,
                                           const float* __restrict__ b2,
                                           const float* __restrict__ W3,
                                           const float* __restrict__ b3) {
  double l0e, l1e;
  mlp64(corr64, W1, b1, W2, b2, W3, b3, l0e, l1e);
  const double G0 = gumbel64_at(2u * base);
  const double G1 = gumbel64_at(2u * base + 1u);
  return (l0e + G0 >= l1e + G1) ? 1.0f : 0.0f;
}

// ---------------------------------------------------------------------------
// K0: build dphi table. grid 513 x 256 -> 131328 threads (>=131073 nodes).
// ---------------------------------------------------------------------------
__global__ __launch_bounds__(256) void build_table_kernel(
    const float* __restrict__ W1, const float* __restrict__ b1,
    const float* __restrict__ W2, const float* __restrict__ b2,
    const float* __restrict__ W3, const float* __restrict__ b3,
    float* __restrict__ tbl) {
  const int i = blockIdx.x * 256 + threadIdx.x;
  if (i > TBL_INTERVALS) return;
  const float x = TBL_MIN + (float)i * (1.0f / TBL_SCALE);  // exact
  tbl[i] = mlp32(x, W1, b1, W2, b2, W3, b3);
}

// ---------------------------------------------------------------------------
// K1: corr[b] = fm[b] @ fm[b]^T with f64 accumulation, f64 output.
// grid (4,4,32), 256 threads. 64x64 tile, BK=32, 4x4 micro-tile.
// ---------------------------------------------------------------------------
__global__ __launch_bounds__(256) void corr_gemm64_kernel(
    const float* __restrict__ fm, double* __restrict__ corr) {
  const int b = blockIdx.z;
  const int row0 = blockIdx.y * 64;
  const int col0 = blockIdx.x * 64;
  const float* base = fm + (size_t)b * 65536;

  __shared__ float As[32][68];  // As[k][m]
  __shared__ float Bs[32][68];  // Bs[k][n]

  const int tid = threadIdx.x;
  const int tx = tid & 15;
  const int ty = tid >> 4;
  const int m = tid >> 2;
  const int c = (tid & 3) * 8;

  double acc[4][4];
#pragma unroll
  for (int i = 0; i < 4; ++i)
#pragma unroll
    for (int j = 0; j < 4; ++j) acc[i][j] = 0.0;

  for (int k0 = 0; k0 < 256; k0 += 32) {
    float4 v0 = *(const float4*)(base + (size_t)(row0 + m) * 256 + k0 + c);
    float4 v1 = *(const float4*)(base + (size_t)(row0 + m) * 256 + k0 + c + 4);
    float4 w0 = *(const float4*)(base + (size_t)(col0 + m) * 256 + k0 + c);
    float4 w1 = *(const float4*)(base + (size_t)(col0 + m) * 256 + k0 + c + 4);
    __syncthreads();
    As[c + 0][m] = v0.x; As[c + 1][m] = v0.y;
    As[c + 2][m] = v0.z; As[c + 3][m] = v0.w;
    As[c + 4][m] = v1.x; As[c + 5][m] = v1.y;
    As[c + 6][m] = v1.z; As[c + 7][m] = v1.w;
    Bs[c + 0][m] = w0.x; Bs[c + 1][m] = w0.y;
    Bs[c + 2][m] = w0.z; Bs[c + 3][m] = w0.w;
    Bs[c + 4][m] = w1.x; Bs[c + 5][m] = w1.y;
    Bs[c + 6][m] = w1.z; Bs[c + 7][m] = w1.w;
    __syncthreads();

#pragma unroll
    for (int kk = 0; kk < 32; ++kk) {
      float a[4], bv[4];
      *(float4*)a = *(const float4*)(&As[kk][ty * 4]);
      *(float4*)bv = *(const float4*)(&Bs[kk][tx * 4]);
      double ad[4], bd[4];
#pragma unroll
      for (int i = 0; i < 4; ++i) {
        ad[i] = (double)a[i];
        bd[i] = (double)bv[i];
      }
#pragma unroll
      for (int i = 0; i < 4; ++i)
#pragma unroll
        for (int j = 0; j < 4; ++j) acc[i][j] = fma(ad[i], bd[j], acc[i][j]);
    }
  }

  double* Cb = corr + (size_t)b * 65536;
#pragma unroll
  for (int i = 0; i < 4; ++i) {
    const int row = row0 + ty * 4 + i;
    double2 o0 = {acc[i][0], acc[i][1]};
    double2 o1 = {acc[i][2], acc[i][3]};
    *(double2*)(Cb + (size_t)row * 256 + col0 + tx * 4) = o0;
    *(double2*)(Cb + (size_t)row * 256 + col0 + tx * 4 + 2) = o1;
  }
}

// ---------------------------------------------------------------------------
// K2: decisions + fused row-normalize. One ELEMENT per thread,
// one row per 256-thread block. grid 8192.
// ---------------------------------------------------------------------------
__global__ __launch_bounds__(256) void decide_norm_kernel(
    const double* __restrict__ corr, const float* __restrict__ tbl,
    const float* __restrict__ W1, const float* __restrict__ b1,
    const float* __restrict__ W2, const float* __restrict__ b2,
    const float* __restrict__ W3, const float* __restrict__ b3,
    float* __restrict__ adj) {
  const int row = blockIdx.x;  // 0..8191  (= b*256 + s)
  const int b = row >> 8;
  const int s = row & 255;
  const int t = threadIdx.x;

  const double corr64 = corr[(size_t)row * 256 + t];
  float a;

  if (t == s) {
    a = 1.0f;
  } else {
    const float cf = (float)corr64;
    const uint32_t base =
        ((uint32_t)b << 16) | ((uint32_t)s << 8) | (uint32_t)t;
    if (fabsf(cf) >= 127.0f) {
      a = decide_exact(corr64, base, W1, b1, W2, b2, W3, b3);
    } else {
      // table lerp for dphi
      const float xf = (cf - TBL_MIN) * TBL_SCALE;
      const int i = (int)xf;
      const float fr = xf - (float)i;
      const float t0v = tbl[i];
      const float t1v = tbl[i + 1];
      const float dphi = fmaf(fr, t1v - t0v, t0v);

      const float g0 = gumbel32_at(2u * base);
      const float g1 = gumbel32_at(2u * base + 1u);
      const float d = dphi - (g1 - g0);
      if (fabsf(d) >= 4e-4f) {
        a = (d >= 0.0f) ? 1.0f : 0.0f;
      } else {
        a = decide_exact(corr64, base, W1, b1, W2, b2, W3, b3);
      }
    }
  }

  // row sum: wave shfl reduce + 4-partial LDS reduce (exact small ints)
  float sum = a;
#pragma unroll
  for (int off = 32; off; off >>= 1) sum += __shfl_xor(sum, off);
  __shared__ float red[4];
  const int w = t >> 6;
  if ((t & 63) == 0) red[w] = sum;
  __syncthreads();
  const float total = red[0] + red[1] + red[2] + red[3];
  const float r = 1.0f / total;

  adj[(size_t)row * 256 + t] = a * r;
}

// ---------------------------------------------------------------------------
// K3/K4: f32 GEMM, M=N=K=256 per batch z. BM=BN=128, BK=8, 256 thr.
// ---------------------------------------------------------------------------
__global__ __launch_bounds__(256) void gemm_kernel(
    const float* __restrict__ A, const float* __restrict__ B,
    const float* __restrict__ bias, float* __restrict__ C,
    int aDiv, int bShared) {
  const int z = blockIdx.z;
  const float* Ab = A + (size_t)(z / aDiv) * 65536;
  const float* Bb = bShared ? B : (B + (size_t)z * 65536);
  float* Cb = C + (size_t)z * 65536;

  const int row0 = blockIdx.y * 128;
  const int col0 = blockIdx.x * 128;

  __shared__ float As[8][132];
  __shared__ float Bs[8][132];

  const int tid = threadIdx.x;
  const int tx = tid & 15;
  const int ty = tid >> 4;

  float acc[2][2][4][4];
#pragma unroll
  for (int a = 0; a < 2; ++a)
#pragma unroll
    for (int bq = 0; bq < 2; ++bq)
#pragma unroll
      for (int i = 0; i < 4; ++i)
#pragma unroll
        for (int j = 0; j < 4; ++j) acc[a][bq][i][j] = 0.0f;

  for (int k0 = 0; k0 < 256; k0 += 8) {
    {
      int r = tid >> 1, c = (tid & 1) * 4;
      float4 v = *(const float4*)(Ab + (size_t)(row0 + r) * 256 + k0 + c);
      As[c + 0][r] = v.x;
      As[c + 1][r] = v.y;
      As[c + 2][r] = v.z;
      As[c + 3][r] = v.w;
    }
    {
      int r = tid >> 5, c = (tid & 31) * 4;
      *(float4*)(&Bs[r][c]) =
          *(const float4*)(Bb + (size_t)(k0 + r) * 256 + col0 + c);
    }
    __syncthreads();

#pragma unroll
    for (int kk = 0; kk < 8; ++kk) {
      float a0[4], a1[4], b0[4], b1[4];
      *(float4*)a0 = *(const float4*)(&As[kk][ty * 4]);
      *(float4*)a1 = *(const float4*)(&As[kk][ty * 4 + 64]);
      *(float4*)b0 = *(const float4*)(&Bs[kk][tx * 4]);
      *(float4*)b1 = *(const float4*)(&Bs[kk][tx * 4 + 64]);
#pragma unroll
      for (int i = 0; i < 4; ++i)
#pragma unroll
        for (int j = 0; j < 4; ++j) {
          acc[0][0][i][j] += a0[i] * b0[j];
          acc[0][1][i][j] += a0[i] * b1[j];
          acc[1][0][i][j] += a1[i] * b0[j];
          acc[1][1][i][j] += a1[i] * b1[j];
        }
    }
    __syncthreads();
  }

#pragma unroll
  for (int ih = 0; ih < 2; ++ih)
#pragma unroll
    for (int i = 0; i < 4; ++i) {
      const int row = row0 + ih * 64 + ty * 4 + i;
#pragma unroll
      for (int jh = 0; jh < 2; ++jh) {
        const int col = col0 + jh * 64 + tx * 4;
        float4 o;
        o.x = acc[ih][jh][i][0];
        o.y = acc[ih][jh][i][1];
        o.z = acc[ih][jh][i][2];
        o.w = acc[ih][jh][i][3];
        if (bias) {
          float4 bv = *(const float4*)(bias + col);
          o.x += bv.x; o.y += bv.y; o.z += bv.z; o.w += bv.w;
        }
        *(float4*)(Cb + (size_t)row * 256 + col) = o;
      }
    }
}

extern "C" void kernel_launch(void* const* d_in, const int* in_sizes, int n_in,
                              void* d_out, int out_size, void* d_ws,
                              size_t ws_size, hipStream_t stream) {
  const float* features = (const float*)d_in[0];
  const float* fm       = (const float*)d_in[1];
  const float* W1 = (const float*)d_in[2];
  const float* b1 = (const float*)d_in[3];
  const float* W2 = (const float*)d_in[4];
  const float* b2 = (const float*)d_in[5];
  const float* W3 = (const float*)d_in[6];
  const float* b3 = (const float*)d_in[7];
  const float* Wl = (const float*)d_in[8];
  const float* bl = (const float*)d_in[9];
  float* out = (float*)d_out;

  // ws layout (43.0 MB):
  //   tbl    @ 0        .. 1.0 MB   (f32, 131073 entries, live all along)
  //   adj    @ 1 MB     .. 9.4 MB   (f32)
  //   corr64 @ 9.4 MB   .. 26.2 MB  (f64, dead after decide_norm)
  //   X      @ 9.4 MB   .. 43.0 MB  (f32, overwrites corr64 - safe)
  char* ws = (char*)d_ws;
  float* tbl     = (float*)ws;
  float* adj     = (float*)(ws + (1u << 20));
  double* corr64 = (double*)(ws + (1u << 20) + 8388608u);
  float* X       = (float*)(ws + (1u << 20) + 8388608u);

  build_table_kernel<<<dim3(513), 256, 0, stream>>>(W1, b1, W2, b2, W3, b3,
                                                    tbl);
  corr_gemm64_kernel<<<dim3(4, 4, 32), 256, 0, stream>>>(fm, corr64);
  decide_norm_kernel<<<dim3(8192), 256, 0, stream>>>(corr64, tbl, W1, b1, W2,
                                                     b2, W3, b3, adj);
  // X[b,c] = adj[b] @ F[b,c]   (X overwrites corr64; corr64 fully consumed)
  gemm_kernel<<<dim3(2, 2, 128), 256, 0, stream>>>(adj, features, nullptr, X,
                                                   4, 0);
  // out[b,c] = X[b,c] @ Wl + bl
  gemm_kernel<<<dim3(2, 2, 128), 256, 0, stream>>>(X, Wl, bl, out, 1, 1);
}

// Round 8
// 137.038 us; speedup vs baseline: 3.4370x; 1.4530x over previous
//
#include <hip/hip_runtime.h>
#include <stdint.h>

// ---------------------------------------------------------------------------
// B=32, C=4, S=256, L=256, Din=Dout=256
// Pipeline:
//   K0 build_table: dphi table (131073 nodes over [-128,128], mlp32 nodes)
//   K1 corr_gemm64: corr[b] = fm[b] @ fm[b]^T, f64 accumulate, f64 store
//   K2 decide_norm: 1 elem/thread: lerp(dphi) + gumbel32 decision,
//                   |margin|>=4e-4 guard, validated mlp64+gumbel64 fallback;
//                   fused row-normalize
//   K3 mfma gemm:   X[b,c] = adj[b] @ F[b,c]      (bf16x3 split MFMA)
//   K4 mfma gemm:   out    = X @ Wl + bl          (bf16x3 split MFMA)
// bf16x3: x = hi + lo (RNE); A@B ~= Ah@Bh + Ah@Bl + Al@Bh, err ~2^-16 rel.
// threefry partitionable (jax key 42): bits(i) = o0^o1 of tf2x32((0,42),(0,i))
// ---------------------------------------------------------------------------

#define TBL_INTERVALS 131072
#define TBL_MIN -128.0f
#define TBL_SCALE 512.0f

typedef __attribute__((ext_vector_type(8))) short short8v;   // 8 bf16
typedef __attribute__((ext_vector_type(4))) short short4v;   // 4 bf16
typedef __attribute__((ext_vector_type(4))) float float4v;   // MFMA acc

__device__ __forceinline__ void threefry2x32(uint32_t x0, uint32_t x1,
                                             uint32_t& o0, uint32_t& o1) {
  const uint32_t ks0 = 0u;
  const uint32_t ks1 = 42u;
  const uint32_t ks2 = 0x1BD11BDAu ^ ks0 ^ ks1;
  const uint32_t ks[3] = {ks0, ks1, ks2};
  const uint32_t rot[2][4] = {{13u, 15u, 26u, 6u}, {17u, 29u, 16u, 24u}};
  x0 += ks0;
  x1 += ks1;
#pragma unroll
  for (int i = 0; i < 5; ++i) {
#pragma unroll
    for (int j = 0; j < 4; ++j) {
      const uint32_t r = rot[i & 1][j];
      x0 += x1;
      x1 = (x1 << r) | (x1 >> (32u - r));
      x1 ^= x0;
    }
    x0 += ks[(i + 1) % 3];
    x1 += ks[(i + 2) % 3] + (uint32_t)(i + 1);
  }
  o0 = x0;
  o1 = x1;
}

__device__ __forceinline__ float uniform_at(uint32_t j) {
  uint32_t o0, o1;
  threefry2x32(0u, j, o0, o1);
  const uint32_t bits = o0 ^ o1;
  uint32_t fb = (bits >> 9) | 0x3F800000u;
  float frac = __uint_as_float(fb) - 1.0f;
  return fmaxf(frac + 1e-10f, 1e-10f);
}

__device__ __forceinline__ double gumbel64_at(uint32_t j) {
  double t = -log((double)uniform_at(j));
  return -log(t);
}

__device__ __forceinline__ float gumbel32_at(uint32_t j) {
  float t = -logf(uniform_at(j));
  return -logf(t);
}

__device__ __forceinline__ double gelu_d(double x) {
  return 0.5 * x * (1.0 + erf(x * 0.70710678118654752440));
}

__device__ __forceinline__ float gelu_f(float x) {
  return 0.5f * x * (1.0f + erff(x * 0.70710678f));
}

// f32 MLP 1->16->8->2, returns l0-l1
__device__ __forceinline__ float mlp32(float corr, const float* __restrict__ W1,
                                       const float* __restrict__ b1,
                                       const float* __restrict__ W2,
                                       const float* __restrict__ b2,
                                       const float* __restrict__ W3,
                                       const float* __restrict__ b3) {
  float h1[16];
#pragma unroll
  for (int u = 0; u < 16; ++u) h1[u] = gelu_f(fmaf(corr, W1[u], b1[u]));
  float h2[8];
#pragma unroll
  for (int v = 0; v < 8; ++v) {
    float x = b2[v];
#pragma unroll
    for (int u = 0; u < 16; ++u) x = fmaf(h1[u], W2[u * 8 + v], x);
    h2[v] = gelu_f(x);
  }
  float l0 = b3[0], l1 = b3[1];
#pragma unroll
  for (int v = 0; v < 8; ++v) {
    l0 = fmaf(h2[v], W3[v * 2 + 0], l0);
    l1 = fmaf(h2[v], W3[v * 2 + 1], l1);
  }
  return l0 - l1;
}

// exact f64 MLP (identical op order to the validated round-2 path)
__device__ __noinline__ void mlp64(double acc, const float* __restrict__ W1,
                                   const float* __restrict__ b1,
                                   const float* __restrict__ W2,
                                   const float* __restrict__ b2,
                                   const float* __restrict__ W3,
                                   const float* __restrict__ b3, double& l0,
                                   double& l1) {
  double h1[16];
#pragma unroll
  for (int i = 0; i < 16; ++i)
    h1[i] = gelu_d(acc * (double)W1[i] + (double)b1[i]);
  double h2[8];
#pragma unroll
  for (int j = 0; j < 8; ++j) {
    double v = (double)b2[j];
#pragma unroll
    for (int i = 0; i < 16; ++i) v += h1[i] * (double)W2[i * 8 + j];
    h2[j] = gelu_d(v);
  }
  l0 = (double)b3[0];
  l1 = (double)b3[1];
#pragma unroll
  for (int j = 0; j < 8; ++j) {
    l0 += h2[j] * (double)W3[j * 2 + 0];
    l1 += h2[j] * (double)W3[j * 2 + 1];
  }
}

__device__ __noinline__ float decide_exact(double corr64, uint32_t base,
                                           const float* __restrict__ W1,
                                           const float* __restrict__ b1,
                                           const float* __restrict__ W2,
                                           const float* __restrict__ b2,
                                           const float* __restrict__ W3,
                                           const float* __restrict__ b3) {
  double l0e, l1e;
  mlp64(corr64, W1, b1, W2, b2, W3, b3, l0e, l1e);
  const double G0 = gumbel64_at(2u * base);
  const double G1 = gumbel64_at(2u * base + 1u);
  return (l0e + G0 >= l1e + G1) ? 1.0f : 0.0f;
}

// RNE f32 -> bf16 split
__device__ __forceinline__ void split_bf16(float x, short& h, short& l) {
  uint32_t u = __float_as_uint(x);
  uint32_t hr = (u + 0x7FFFu + ((u >> 16) & 1u)) >> 16;
  float hf = __uint_as_float(hr << 16);
  float lo = x - hf;
  uint32_t v = __float_as_uint(lo);
  uint32_t lr = (v + 0x7FFFu + ((v >> 16) & 1u)) >> 16;
  h = (short)hr;
  l = (short)lr;
}

// ---------------------------------------------------------------------------
// K0: build dphi table.
// ---------------------------------------------------------------------------
__global__ __launch_bounds__(256) void build_table_kernel(
    const float* __restrict__ W1, const float* __restrict__ b1,
    const float* __restrict__ W2, const float* __restrict__ b2,
    const float* __restrict__ W3, const float* __restrict__ b3,
    float* __restrict__ tbl) {
  const int i = blockIdx.x * 256 + threadIdx.x;
  if (i > TBL_INTERVALS) return;
  const float x = TBL_MIN + (float)i * (1.0f / TBL_SCALE);
  tbl[i] = mlp32(x, W1, b1, W2, b2, W3, b3);
}

// ---------------------------------------------------------------------------
// K1: corr[b] = fm[b] @ fm[b]^T with f64 accumulation, f64 output.
// ---------------------------------------------------------------------------
__global__ __launch_bounds__(256) void corr_gemm64_kernel(
    const float* __restrict__ fm, double* __restrict__ corr) {
  const int b = blockIdx.z;
  const int row0 = blockIdx.y * 64;
  const int col0 = blockIdx.x * 64;
  const float* base = fm + (size_t)b * 65536;

  __shared__ float As[32][68];
  __shared__ float Bs[32][68];

  const int tid = threadIdx.x;
  const int tx = tid & 15;
  const int ty = tid >> 4;
  const int m = tid >> 2;
  const int c = (tid & 3) * 8;

  double acc[4][4];
#pragma unroll
  for (int i = 0; i < 4; ++i)
#pragma unroll
    for (int j = 0; j < 4; ++j) acc[i][j] = 0.0;

  for (int k0 = 0; k0 < 256; k0 += 32) {
    float4 v0 = *(const float4*)(base + (size_t)(row0 + m) * 256 + k0 + c);
    float4 v1 = *(const float4*)(base + (size_t)(row0 + m) * 256 + k0 + c + 4);
    float4 w0 = *(const float4*)(base + (size_t)(col0 + m) * 256 + k0 + c);
    float4 w1 = *(const float4*)(base + (size_t)(col0 + m) * 256 + k0 + c + 4);
    __syncthreads();
    As[c + 0][m] = v0.x; As[c + 1][m] = v0.y;
    As[c + 2][m] = v0.z; As[c + 3][m] = v0.w;
    As[c + 4][m] = v1.x; As[c + 5][m] = v1.y;
    As[c + 6][m] = v1.z; As[c + 7][m] = v1.w;
    Bs[c + 0][m] = w0.x; Bs[c + 1][m] = w0.y;
    Bs[c + 2][m] = w0.z; Bs[c + 3][m] = w0.w;
    Bs[c + 4][m] = w1.x; Bs[c + 5][m] = w1.y;
    Bs[c + 6][m] = w1.z; Bs[c + 7][m] = w1.w;
    __syncthreads();

#pragma unroll
    for (int kk = 0; kk < 32; ++kk) {
      float a[4], bv[4];
      *(float4*)a = *(const float4*)(&As[kk][ty * 4]);
      *(float4*)bv = *(const float4*)(&Bs[kk][tx * 4]);
      double ad[4], bd[4];
#pragma unroll
      for (int i = 0; i < 4; ++i) {
        ad[i] = (double)a[i];
        bd[i] = (double)bv[i];
      }
#pragma unroll
      for (int i = 0; i < 4; ++i)
#pragma unroll
        for (int j = 0; j < 4; ++j) acc[i][j] = fma(ad[i], bd[j], acc[i][j]);
    }
  }

  double* Cb = corr + (size_t)b * 65536;
#pragma unroll
  for (int i = 0; i < 4; ++i) {
    const int row = row0 + ty * 4 + i;
    double2 o0 = {acc[i][0], acc[i][1]};
    double2 o1 = {acc[i][2], acc[i][3]};
    *(double2*)(Cb + (size_t)row * 256 + col0 + tx * 4) = o0;
    *(double2*)(Cb + (size_t)row * 256 + col0 + tx * 4 + 2) = o1;
  }
}

// ---------------------------------------------------------------------------
// K2: decisions + fused row-normalize. One element per thread.
// ---------------------------------------------------------------------------
__global__ __launch_bounds__(256) void decide_norm_kernel(
    const double* __restrict__ corr, const float* __restrict__ tbl,
    const float* __restrict__ W1, const float* __restrict__ b1,
    const float* __restrict__ W2, const float* __restrict__ b2,
    const float* __restrict__ W3, const float* __restrict__ b3,
    float* __restrict__ adj) {
  const int row = blockIdx.x;
  const int b = row >> 8;
  const int s = row & 255;
  const int t = threadIdx.x;

  const double corr64 = corr[(size_t)row * 256 + t];
  float a;

  if (t == s) {
    a = 1.0f;
  } else {
    const float cf = (float)corr64;
    const uint32_t base =
        ((uint32_t)b << 16) | ((uint32_t)s << 8) | (uint32_t)t;
    if (fabsf(cf) >= 127.0f) {
      a = decide_exact(corr64, base, W1, b1, W2, b2, W3, b3);
    } else {
      const float xf = (cf - TBL_MIN) * TBL_SCALE;
      const int i = (int)xf;
      const float fr = xf - (float)i;
      const float t0v = tbl[i];
      const float t1v = tbl[i + 1];
      const float dphi = fmaf(fr, t1v - t0v, t0v);

      const float g0 = gumbel32_at(2u * base);
      const float g1 = gumbel32_at(2u * base + 1u);
      const float d = dphi - (g1 - g0);
      if (fabsf(d) >= 4e-4f) {
        a = (d >= 0.0f) ? 1.0f : 0.0f;
      } else {
        a = decide_exact(corr64, base, W1, b1, W2, b2, W3, b3);
      }
    }
  }

  float sum = a;
#pragma unroll
  for (int off = 32; off; off >>= 1) sum += __shfl_xor(sum, off);
  __shared__ float red[4];
  const int w = t >> 6;
  if ((t & 63) == 0) red[w] = sum;
  __syncthreads();
  const float total = red[0] + red[1] + red[2] + red[3];
  const float r = 1.0f / total;

  adj[(size_t)row * 256 + t] = a * r;
}

// ---------------------------------------------------------------------------
// K3/K4: bf16x3 split MFMA GEMM. M=N=K=256 per batch z.
// 128x128 tile, BK=32, 4 waves x (64x64), mfma_f32_16x16x32_bf16.
// LDS [row][40] bf16 (80B stride: b128-aligned, 2-way banks max).
// B stored transposed in LDS ([n][k]) for contiguous-k frag reads.
// ---------------------------------------------------------------------------
__global__ __launch_bounds__(256) void gemm_mfma_kernel(
    const float* __restrict__ A, const float* __restrict__ B,
    const float* __restrict__ bias, float* __restrict__ C,
    int aDiv, int bShared) {
  const int z = blockIdx.z;
  const float* Ab = A + (size_t)(z / aDiv) * 65536;
  const float* Bb = bShared ? B : (B + (size_t)z * 65536);
  float* Cb = C + (size_t)z * 65536;

  const int row0 = blockIdx.y * 128;
  const int col0 = blockIdx.x * 128;

  __shared__ short Ah[128][40];
  __shared__ short Al[128][40];
  __shared__ short Bh[128][40];  // transposed: [n][k]
  __shared__ short Bl[128][40];

  const int tid = threadIdx.x;
  const int w = tid >> 6;
  const int wr = (w >> 1) * 64;  // wave row offset in tile
  const int wc = (w & 1) * 64;   // wave col offset in tile
  const int lane = tid & 63;
  const int fcol = lane & 15;
  const int kg = lane >> 4;  // 0..3

  // A staging: thread -> row am, k-half ak (16 elems)
  const int am = tid >> 1;
  const int ak = (tid & 1) * 16;
  // B staging: thread -> 4 cols (nq..nq+3) x 4 ks (kb..kb+3)
  const int nq = (tid & 31) * 4;
  const int kb = (tid >> 5) * 4;

  float4v acc[4][4];
#pragma unroll
  for (int i = 0; i < 4; ++i)
#pragma unroll
    for (int j = 0; j < 4; ++j) acc[i][j] = (float4v)(0.0f);

  for (int k0 = 0; k0 < 256; k0 += 32) {
    // ---- global loads (before barrier, overlap with prior compute) ----
    float4 av[4];
#pragma unroll
    for (int q = 0; q < 4; ++q)
      av[q] = *(const float4*)(Ab + (size_t)(row0 + am) * 256 + k0 + ak + q * 4);
    float4 bv[4];
#pragma unroll
    for (int j = 0; j < 4; ++j)
      bv[j] = *(const float4*)(Bb + (size_t)(k0 + kb + j) * 256 + col0 + nq);

    __syncthreads();  // prior K-step's frag reads complete

    // ---- convert + LDS write ----
    {
      short h[16], l[16];
#pragma unroll
      for (int q = 0; q < 4; ++q) {
        split_bf16(av[q].x, h[q * 4 + 0], l[q * 4 + 0]);
        split_bf16(av[q].y, h[q * 4 + 1], l[q * 4 + 1]);
        split_bf16(av[q].z, h[q * 4 + 2], l[q * 4 + 2]);
        split_bf16(av[q].w, h[q * 4 + 3], l[q * 4 + 3]);
      }
      *(short8v*)&Ah[am][ak] = *(short8v*)&h[0];
      *(short8v*)&Ah[am][ak + 8] = *(short8v*)&h[8];
      *(short8v*)&Al[am][ak] = *(short8v*)&l[0];
      *(short8v*)&Al[am][ak + 8] = *(short8v*)&l[8];
    }
    {
      // bv[j] components i -> element (k=kb+j, n=nq+i)
      const float bm[4][4] = {{bv[0].x, bv[1].x, bv[2].x, bv[3].x},
                              {bv[0].y, bv[1].y, bv[2].y, bv[3].y},
                              {bv[0].z, bv[1].z, bv[2].z, bv[3].z},
                              {bv[0].w, bv[1].w, bv[2].w, bv[3].w}};
#pragma unroll
      for (int i = 0; i < 4; ++i) {
        short h[4], l[4];
#pragma unroll
        for (int j = 0; j < 4; ++j) split_bf16(bm[i][j], h[j], l[j]);
        *(short4v*)&Bh[nq + i][kb] = *(short4v*)&h[0];
        *(short4v*)&Bl[nq + i][kb] = *(short4v*)&l[0];
      }
    }
    __syncthreads();

    // ---- frag reads + 48 MFMAs ----
    short8v afh[4], afl[4], bfh[4], bfl[4];
#pragma unroll
    for (int im = 0; im < 4; ++im) {
      const int r = wr + im * 16 + fcol;
      afh[im] = *(const short8v*)&Ah[r][kg * 8];
      afl[im] = *(const short8v*)&Al[r][kg * 8];
    }
#pragma unroll
    for (int in = 0; in < 4; ++in) {
      const int n = wc + in * 16 + fcol;
      bfh[in] = *(const short8v*)&Bh[n][kg * 8];
      bfl[in] = *(const short8v*)&Bl[n][kg * 8];
    }
#pragma unroll
    for (int im = 0; im < 4; ++im)
#pragma unroll
      for (int in = 0; in < 4; ++in) {
        acc[im][in] = __builtin_amdgcn_mfma_f32_16x16x32_bf16(
            afh[im], bfh[in], acc[im][in], 0, 0, 0);
        acc[im][in] = __builtin_amdgcn_mfma_f32_16x16x32_bf16(
            afh[im], bfl[in], acc[im][in], 0, 0, 0);
        acc[im][in] = __builtin_amdgcn_mfma_f32_16x16x32_bf16(
            afl[im], bfh[in], acc[im][in], 0, 0, 0);
      }
  }

  // ---- epilogue: C layout col=lane&15, row=(lane>>4)*4+reg ----
#pragma unroll
  for (int in = 0; in < 4; ++in) {
    const int col = col0 + wc + in * 16 + fcol;
    const float bvx = bias ? bias[col] : 0.0f;
#pragma unroll
    for (int im = 0; im < 4; ++im) {
      const int rbase = row0 + wr + im * 16 + kg * 4;
#pragma unroll
      for (int r = 0; r < 4; ++r)
        Cb[(size_t)(rbase + r) * 256 + col] = acc[im][in][r] + bvx;
    }
  }
}

extern "C" void kernel_launch(void* const* d_in, const int* in_sizes, int n_in,
                              void* d_out, int out_size, void* d_ws,
                              size_t ws_size, hipStream_t stream) {
  const float* features = (const float*)d_in[0];
  const float* fm       = (const float*)d_in[1];
  const float* W1 = (const float*)d_in[2];
  const float* b1 = (const float*)d_in[3];
  const float* W2 = (const float*)d_in[4];
  const float* b2 = (const float*)d_in[5];
  const float* W3 = (const float*)d_in[6];
  const float* b3 = (const float*)d_in[7];
  const float* Wl = (const float*)d_in[8];
  const float* bl = (const float*)d_in[9];
  float* out = (float*)d_out;

  // ws layout (43.0 MB):
  //   tbl    @ 0        .. 1.0 MB
  //   adj    @ 1 MB     .. 9.4 MB
  //   corr64 @ 9.4 MB   .. 26.2 MB  (dead after decide_norm)
  //   X      @ 9.4 MB   .. 43.0 MB  (overwrites corr64 - safe)
  char* ws = (char*)d_ws;
  float* tbl     = (float*)ws;
  float* adj     = (float*)(ws + (1u << 20));
  double* corr64 = (double*)(ws + (1u << 20) + 8388608u);
  float* X       = (float*)(ws + (1u << 20) + 8388608u);

  build_table_kernel<<<dim3(513), 256, 0, stream>>>(W1, b1, W2, b2, W3, b3,
                                                    tbl);
  corr_gemm64_kernel<<<dim3(4, 4, 32), 256, 0, stream>>>(fm, corr64);
  decide_norm_kernel<<<dim3(8192), 256, 0, stream>>>(corr64, tbl, W1, b1, W2,
                                                     b2, W3, b3, adj);
  // X[b,c] = adj[b] @ F[b,c]
  gemm_mfma_kernel<<<dim3(2, 2, 128), 256, 0, stream>>>(adj, features, nullptr,
                                                        X, 4, 0);
  // out[b,c] = X[b,c] @ Wl + bl
  gemm_mfma_kernel<<<dim3(2, 2, 128), 256, 0, stream>>>(X, Wl, bl, out, 1, 1);
}

// Round 10
// 120.952 us; speedup vs baseline: 3.8941x; 1.1330x over previous
//
#include <hip/hip_runtime.h>
#include <stdint.h>

// ---------------------------------------------------------------------------
// B=32, C=4, S=256, L=256, Din=Dout=256
// Pipeline:
//   K0  build_table: dphi table (131073 nodes over [-128,128], mlp32 nodes)
//   Ki  init: zero worklist counter
//   K1  corr_gemm64: corr[b] = fm[b] @ fm[b]^T, f64 accumulate/store
//   K2f decide_fast: elementwise lerp+gumbel32 decision, |margin|>=4e-4
//       guard; pendings -> worklist, adj_bin in {0,1}.  ONE thread per
//       adjacency ELEMENT: grid 8192 x 256 = 2,097,152 (NOT 2x - round-9 bug)
//   K2b decide_exact: packed f64 resolve of worklist (validated mlp64 path)
//   K2c rowscale: rs[row] = 1.0f / rowsum(adj_bin)
//   K3  gemm_binA: X[b,c] = rs * (adj_bin[b] @ F[b,c])   (exact-bf16 A, 2-term B)
//   K4  gemm_mfma: out = X @ Wl + bl                     (bf16x3, 3-term)
// threefry partitionable (jax key 42): bits(i) = o0^o1 of tf2x32((0,42),(0,i))
// ---------------------------------------------------------------------------

#define TBL_INTERVALS 131072
#define TBL_MIN -128.0f
#define TBL_SCALE 512.0f
#define WL_CAP 131072u

typedef __attribute__((ext_vector_type(8))) short short8v;
typedef __attribute__((ext_vector_type(4))) short short4v;
typedef __attribute__((ext_vector_type(4))) float float4v;

__device__ __forceinline__ void threefry2x32(uint32_t x0, uint32_t x1,
                                             uint32_t& o0, uint32_t& o1) {
  const uint32_t ks0 = 0u;
  const uint32_t ks1 = 42u;
  const uint32_t ks2 = 0x1BD11BDAu ^ ks0 ^ ks1;
  const uint32_t ks[3] = {ks0, ks1, ks2};
  const uint32_t rot[2][4] = {{13u, 15u, 26u, 6u}, {17u, 29u, 16u, 24u}};
  x0 += ks0;
  x1 += ks1;
#pragma unroll
  for (int i = 0; i < 5; ++i) {
#pragma unroll
    for (int j = 0; j < 4; ++j) {
      const uint32_t r = rot[i & 1][j];
      x0 += x1;
      x1 = (x1 << r) | (x1 >> (32u - r));
      x1 ^= x0;
    }
    x0 += ks[(i + 1) % 3];
    x1 += ks[(i + 2) % 3] + (uint32_t)(i + 1);
  }
  o0 = x0;
  o1 = x1;
}

__device__ __forceinline__ float uniform_at(uint32_t j) {
  uint32_t o0, o1;
  threefry2x32(0u, j, o0, o1);
  const uint32_t bits = o0 ^ o1;
  uint32_t fb = (bits >> 9) | 0x3F800000u;
  float frac = __uint_as_float(fb) - 1.0f;
  return fmaxf(frac + 1e-10f, 1e-10f);
}

__device__ __forceinline__ double gumbel64_at(uint32_t j) {
  double t = -log((double)uniform_at(j));
  return -log(t);
}

__device__ __forceinline__ float gumbel32_at(uint32_t j) {
  float t = -logf(uniform_at(j));
  return -logf(t);
}

__device__ __forceinline__ double gelu_d(double x) {
  return 0.5 * x * (1.0 + erf(x * 0.70710678118654752440));
}

__device__ __forceinline__ float gelu_f(float x) {
  return 0.5f * x * (1.0f + erff(x * 0.70710678f));
}

__device__ __forceinline__ float mlp32(float corr, const float* __restrict__ W1,
                                       const float* __restrict__ b1,
                                       const float* __restrict__ W2,
                                       const float* __restrict__ b2,
                                       const float* __restrict__ W3,
                                       const float* __restrict__ b3) {
  float h1[16];
#pragma unroll
  for (int u = 0; u < 16; ++u) h1[u] = gelu_f(fmaf(corr, W1[u], b1[u]));
  float h2[8];
#pragma unroll
  for (int v = 0; v < 8; ++v) {
    float x = b2[v];
#pragma unroll
    for (int u = 0; u < 16; ++u) x = fmaf(h1[u], W2[u * 8 + v], x);
    h2[v] = gelu_f(x);
  }
  float l0 = b3[0], l1 = b3[1];
#pragma unroll
  for (int v = 0; v < 8; ++v) {
    l0 = fmaf(h2[v], W3[v * 2 + 0], l0);
    l1 = fmaf(h2[v], W3[v * 2 + 1], l1);
  }
  return l0 - l1;
}

// exact f64 MLP (validated path, rounds 2-8)
__device__ __forceinline__ void mlp64(double acc, const float* __restrict__ W1,
                                      const float* __restrict__ b1,
                                      const float* __restrict__ W2,
                                      const float* __restrict__ b2,
                                      const float* __restrict__ W3,
                                      const float* __restrict__ b3, double& l0,
                                      double& l1) {
  double h1[16];
#pragma unroll
  for (int i = 0; i < 16; ++i)
    h1[i] = gelu_d(acc * (double)W1[i] + (double)b1[i]);
  double h2[8];
#pragma unroll
  for (int j = 0; j < 8; ++j) {
    double v = (double)b2[j];
#pragma unroll
    for (int i = 0; i < 16; ++i) v += h1[i] * (double)W2[i * 8 + j];
    h2[j] = gelu_d(v);
  }
  l0 = (double)b3[0];
  l1 = (double)b3[1];
#pragma unroll
  for (int j = 0; j < 8; ++j) {
    l0 += h2[j] * (double)W3[j * 2 + 0];
    l1 += h2[j] * (double)W3[j * 2 + 1];
  }
}

// RNE f32 -> bf16 split
__device__ __forceinline__ void split_bf16(float x, short& h, short& l) {
  uint32_t u = __float_as_uint(x);
  uint32_t hr = (u + 0x7FFFu + ((u >> 16) & 1u)) >> 16;
  float hf = __uint_as_float(hr << 16);
  float lo = x - hf;
  uint32_t v = __float_as_uint(lo);
  uint32_t lr = (v + 0x7FFFu + ((v >> 16) & 1u)) >> 16;
  h = (short)hr;
  l = (short)lr;
}

__device__ __forceinline__ short bf16_exact(float x) {
  // for values exactly representable in bf16 (0.0f / 1.0f)
  return (short)(__float_as_uint(x) >> 16);
}

// ---------------------------------------------------------------------------
__global__ __launch_bounds__(256) void build_table_kernel(
    const float* __restrict__ W1, const float* __restrict__ b1,
    const float* __restrict__ W2, const float* __restrict__ b2,
    const float* __restrict__ W3, const float* __restrict__ b3,
    float* __restrict__ tbl) {
  const int i = blockIdx.x * 256 + threadIdx.x;
  if (i > TBL_INTERVALS) return;
  const float x = TBL_MIN + (float)i * (1.0f / TBL_SCALE);
  tbl[i] = mlp32(x, W1, b1, W2, b2, W3, b3);
}

__global__ void init_counter_kernel(uint32_t* __restrict__ c) { c[0] = 0u; }

// ---------------------------------------------------------------------------
// K1: corr[b] = fm[b] @ fm[b]^T, f64 accumulate, f64 store.
// ---------------------------------------------------------------------------
__global__ __launch_bounds__(256) void corr_gemm64_kernel(
    const float* __restrict__ fm, double* __restrict__ corr) {
  const int b = blockIdx.z;
  const int row0 = blockIdx.y * 64;
  const int col0 = blockIdx.x * 64;
  const float* base = fm + (size_t)b * 65536;

  __shared__ float As[32][68];
  __shared__ float Bs[32][68];

  const int tid = threadIdx.x;
  const int tx = tid & 15;
  const int ty = tid >> 4;
  const int m = tid >> 2;
  const int c = (tid & 3) * 8;

  double acc[4][4];
#pragma unroll
  for (int i = 0; i < 4; ++i)
#pragma unroll
    for (int j = 0; j < 4; ++j) acc[i][j] = 0.0;

  for (int k0 = 0; k0 < 256; k0 += 32) {
    float4 v0 = *(const float4*)(base + (size_t)(row0 + m) * 256 + k0 + c);
    float4 v1 = *(const float4*)(base + (size_t)(row0 + m) * 256 + k0 + c + 4);
    float4 w0 = *(const float4*)(base + (size_t)(col0 + m) * 256 + k0 + c);
    float4 w1 = *(const float4*)(base + (size_t)(col0 + m) * 256 + k0 + c + 4);
    __syncthreads();
    As[c + 0][m] = v0.x; As[c + 1][m] = v0.y;
    As[c + 2][m] = v0.z; As[c + 3][m] = v0.w;
    As[c + 4][m] = v1.x; As[c + 5][m] = v1.y;
    As[c + 6][m] = v1.z; As[c + 7][m] = v1.w;
    Bs[c + 0][m] = w0.x; Bs[c + 1][m] = w0.y;
    Bs[c + 2][m] = w0.z; Bs[c + 3][m] = w0.w;
    Bs[c + 4][m] = w1.x; Bs[c + 5][m] = w1.y;
    Bs[c + 6][m] = w1.z; Bs[c + 7][m] = w1.w;
    __syncthreads();

#pragma unroll
    for (int kk = 0; kk < 32; ++kk) {
      float a[4], bv[4];
      *(float4*)a = *(const float4*)(&As[kk][ty * 4]);
      *(float4*)bv = *(const float4*)(&Bs[kk][tx * 4]);
      double ad[4], bd[4];
#pragma unroll
      for (int i = 0; i < 4; ++i) {
        ad[i] = (double)a[i];
        bd[i] = (double)bv[i];
      }
#pragma unroll
      for (int i = 0; i < 4; ++i)
#pragma unroll
        for (int j = 0; j < 4; ++j) acc[i][j] = fma(ad[i], bd[j], acc[i][j]);
    }
  }

  double* Cb = corr + (size_t)b * 65536;
#pragma unroll
  for (int i = 0; i < 4; ++i) {
    const int row = row0 + ty * 4 + i;
    double2 o0 = {acc[i][0], acc[i][1]};
    double2 o1 = {acc[i][2], acc[i][3]};
    *(double2*)(Cb + (size_t)row * 256 + col0 + tx * 4) = o0;
    *(double2*)(Cb + (size_t)row * 256 + col0 + tx * 4 + 2) = o1;
  }
}

// ---------------------------------------------------------------------------
// K2f: lean elementwise fast decision. One thread per adjacency ELEMENT.
// grid 8192 x 256 = 2,097,152 threads (= B*S*S).
// ---------------------------------------------------------------------------
__global__ __launch_bounds__(256) void decide_fast_kernel(
    const double* __restrict__ corr, const float* __restrict__ tbl,
    float* __restrict__ adj_bin, uint32_t* __restrict__ counter,
    uint32_t* __restrict__ worklist) {
  const uint32_t flat = blockIdx.x * 256u + threadIdx.x;  // < 2,097,152
  const int t = flat & 255;
  const int s = (flat >> 8) & 255;

  float a = 1.0f;
  bool pend = false;
  if (t != s) {
    const float cf = (float)corr[flat];
    if (fabsf(cf) >= 127.0f) {
      pend = true;
      a = 0.0f;
    } else {
      const float xf = (cf - TBL_MIN) * TBL_SCALE;
      const int i = (int)xf;
      const float fr = xf - (float)i;
      const float t0v = tbl[i];
      const float t1v = tbl[i + 1];
      const float dphi = fmaf(fr, t1v - t0v, t0v);

      const float g0 = gumbel32_at(2u * flat);
      const float g1 = gumbel32_at(2u * flat + 1u);
      const float d = dphi - (g1 - g0);
      if (fabsf(d) >= 4e-4f) {
        a = (d >= 0.0f) ? 1.0f : 0.0f;
      } else {
        pend = true;
        a = 0.0f;
      }
    }
  }
  if (pend) {
    const uint32_t idx = atomicAdd(counter, 1u);
    if (idx < WL_CAP) worklist[idx] = flat;
  }
  adj_bin[flat] = a;
}

// ---------------------------------------------------------------------------
// K2b: packed exact f64 resolve of the worklist. grid 64 x 64.
// ---------------------------------------------------------------------------
__global__ __launch_bounds__(64) void decide_exact_kernel(
    const double* __restrict__ corr, const uint32_t* __restrict__ counter,
    const uint32_t* __restrict__ worklist,
    const float* __restrict__ W1, const float* __restrict__ b1,
    const float* __restrict__ W2, const float* __restrict__ b2,
    const float* __restrict__ W3, const float* __restrict__ b3,
    float* __restrict__ adj_bin) {
  const uint32_t n = min(counter[0], WL_CAP);
  for (uint32_t i = blockIdx.x * 64u + threadIdx.x; i < n;
       i += gridDim.x * 64u) {
    const uint32_t flat = worklist[i];
    double l0e, l1e;
    mlp64(corr[flat], W1, b1, W2, b2, W3, b3, l0e, l1e);
    const double G0 = gumbel64_at(2u * flat);
    const double G1 = gumbel64_at(2u * flat + 1u);
    adj_bin[flat] = (l0e + G0 >= l1e + G1) ? 1.0f : 0.0f;
  }
}

// ---------------------------------------------------------------------------
// K2c: rowscale. One wave per row; grid 2048 x 256.
// ---------------------------------------------------------------------------
__global__ __launch_bounds__(256) void rowscale_kernel(
    const float* __restrict__ adj_bin, float* __restrict__ rs) {
  const int row = blockIdx.x * 4 + (threadIdx.x >> 6);
  const int lane = threadIdx.x & 63;
  float4 v = ((const float4*)(adj_bin + (size_t)row * 256))[lane];
  float sum = v.x + v.y + v.z + v.w;
#pragma unroll
  for (int off = 32; off; off >>= 1) sum += __shfl_xor(sum, off);
  if (lane == 0) rs[row] = 1.0f / sum;
}

// ---------------------------------------------------------------------------
// K3: X[b,c] = rs * (adj_bin[b] @ F[b,c]). A is exact-bf16 binary (1 term),
// B split hi+lo (2 terms) -> 32 MFMA / K-step. Epilogue row-scale.
// ---------------------------------------------------------------------------
__global__ __launch_bounds__(256) void gemm_binA_kernel(
    const float* __restrict__ A, const float* __restrict__ B,
    const float* __restrict__ rs, float* __restrict__ C) {
  const int z = blockIdx.z;
  const float* Ab = A + (size_t)(z / 4) * 65536;
  const float* Bb = B + (size_t)z * 65536;
  const float* rsb = rs + (size_t)(z / 4) * 256;
  float* Cb = C + (size_t)z * 65536;

  const int row0 = blockIdx.y * 128;
  const int col0 = blockIdx.x * 128;

  __shared__ short Ah[128][40];
  __shared__ short Bh[128][40];  // transposed: [n][k]
  __shared__ short Bl[128][40];

  const int tid = threadIdx.x;
  const int w = tid >> 6;
  const int wr = (w >> 1) * 64;
  const int wc = (w & 1) * 64;
  const int lane = tid & 63;
  const int fcol = lane & 15;
  const int kg = lane >> 4;

  const int am = tid >> 1;
  const int ak = (tid & 1) * 16;
  const int nq = (tid & 31) * 4;
  const int kb = (tid >> 5) * 4;

  float4v acc[4][4];
#pragma unroll
  for (int i = 0; i < 4; ++i)
#pragma unroll
    for (int j = 0; j < 4; ++j) acc[i][j] = (float4v)(0.0f);

  for (int k0 = 0; k0 < 256; k0 += 32) {
    float4 av[4];
#pragma unroll
    for (int q = 0; q < 4; ++q)
      av[q] = *(const float4*)(Ab + (size_t)(row0 + am) * 256 + k0 + ak + q * 4);
    float4 bv[4];
#pragma unroll
    for (int j = 0; j < 4; ++j)
      bv[j] = *(const float4*)(Bb + (size_t)(k0 + kb + j) * 256 + col0 + nq);

    __syncthreads();

    {
      short h[16];
#pragma unroll
      for (int q = 0; q < 4; ++q) {
        h[q * 4 + 0] = bf16_exact(av[q].x);
        h[q * 4 + 1] = bf16_exact(av[q].y);
        h[q * 4 + 2] = bf16_exact(av[q].z);
        h[q * 4 + 3] = bf16_exact(av[q].w);
      }
      *(short8v*)&Ah[am][ak] = *(short8v*)&h[0];
      *(short8v*)&Ah[am][ak + 8] = *(short8v*)&h[8];
    }
    {
      const float bm[4][4] = {{bv[0].x, bv[1].x, bv[2].x, bv[3].x},
                              {bv[0].y, bv[1].y, bv[2].y, bv[3].y},
                              {bv[0].z, bv[1].z, bv[2].z, bv[3].z},
                              {bv[0].w, bv[1].w, bv[2].w, bv[3].w}};
#pragma unroll
      for (int i = 0; i < 4; ++i) {
        short h[4], l[4];
#pragma unroll
        for (int j = 0; j < 4; ++j) split_bf16(bm[i][j], h[j], l[j]);
        *(short4v*)&Bh[nq + i][kb] = *(short4v*)&h[0];
        *(short4v*)&Bl[nq + i][kb] = *(short4v*)&l[0];
      }
    }
    __syncthreads();

    short8v afh[4], bfh[4], bfl[4];
#pragma unroll
    for (int im = 0; im < 4; ++im)
      afh[im] = *(const short8v*)&Ah[wr + im * 16 + fcol][kg * 8];
#pragma unroll
    for (int in = 0; in < 4; ++in) {
      bfh[in] = *(const short8v*)&Bh[wc + in * 16 + fcol][kg * 8];
      bfl[in] = *(const short8v*)&Bl[wc + in * 16 + fcol][kg * 8];
    }
#pragma unroll
    for (int im = 0; im < 4; ++im)
#pragma unroll
      for (int in = 0; in < 4; ++in) {
        acc[im][in] = __builtin_amdgcn_mfma_f32_16x16x32_bf16(
            afh[im], bfh[in], acc[im][in], 0, 0, 0);
        acc[im][in] = __builtin_amdgcn_mfma_f32_16x16x32_bf16(
            afh[im], bfl[in], acc[im][in], 0, 0, 0);
      }
  }

#pragma unroll
  for (int im = 0; im < 4; ++im) {
    const int rbase = row0 + wr + im * 16 + kg * 4;
    float rsv[4];
#pragma unroll
    for (int r = 0; r < 4; ++r) rsv[r] = rsb[rbase + r];
#pragma unroll
    for (int in = 0; in < 4; ++in) {
      const int col = col0 + wc + in * 16 + fcol;
#pragma unroll
      for (int r = 0; r < 4; ++r)
        Cb[(size_t)(rbase + r) * 256 + col] = acc[im][in][r] * rsv[r];
    }
  }
}

// ---------------------------------------------------------------------------
// K4: out = X @ Wl + bl. bf16x3 (3-term) MFMA.
// ---------------------------------------------------------------------------
__global__ __launch_bounds__(256) void gemm_mfma_kernel(
    const float* __restrict__ A, const float* __restrict__ B,
    const float* __restrict__ bias, float* __restrict__ C) {
  const int z = blockIdx.z;
  const float* Ab = A + (size_t)z * 65536;
  const float* Bb = B;  // shared Wl
  float* Cb = C + (size_t)z * 65536;

  const int row0 = blockIdx.y * 128;
  const int col0 = blockIdx.x * 128;

  __shared__ short Ah[128][40];
  __shared__ short Al[128][40];
  __shared__ short Bh[128][40];
  __shared__ short Bl[128][40];

  const int tid = threadIdx.x;
  const int w = tid >> 6;
  const int wr = (w >> 1) * 64;
  const int wc = (w & 1) * 64;
  const int lane = tid & 63;
  const int fcol = lane & 15;
  const int kg = lane >> 4;

  const int am = tid >> 1;
  const int ak = (tid & 1) * 16;
  const int nq = (tid & 31) * 4;
  const int kb = (tid >> 5) * 4;

  float4v acc[4][4];
#pragma unroll
  for (int i = 0; i < 4; ++i)
#pragma unroll
    for (int j = 0; j < 4; ++j) acc[i][j] = (float4v)(0.0f);

  for (int k0 = 0; k0 < 256; k0 += 32) {
    float4 av[4];
#pragma unroll
    for (int q = 0; q < 4; ++q)
      av[q] = *(const float4*)(Ab + (size_t)(row0 + am) * 256 + k0 + ak + q * 4);
    float4 bv[4];
#pragma unroll
    for (int j = 0; j < 4; ++j)
      bv[j] = *(const float4*)(Bb + (size_t)(k0 + kb + j) * 256 + col0 + nq);

    __syncthreads();

    {
      short h[16], l[16];
#pragma unroll
      for (int q = 0; q < 4; ++q) {
        split_bf16(av[q].x, h[q * 4 + 0], l[q * 4 + 0]);
        split_bf16(av[q].y, h[q * 4 + 1], l[q * 4 + 1]);
        split_bf16(av[q].z, h[q * 4 + 2], l[q * 4 + 2]);
        split_bf16(av[q].w, h[q * 4 + 3], l[q * 4 + 3]);
      }
      *(short8v*)&Ah[am][ak] = *(short8v*)&h[0];
      *(short8v*)&Ah[am][ak + 8] = *(short8v*)&h[8];
      *(short8v*)&Al[am][ak] = *(short8v*)&l[0];
      *(short8v*)&Al[am][ak + 8] = *(short8v*)&l[8];
    }
    {
      const float bm[4][4] = {{bv[0].x, bv[1].x, bv[2].x, bv[3].x},
                              {bv[0].y, bv[1].y, bv[2].y, bv[3].y},
                              {bv[0].z, bv[1].z, bv[2].z, bv[3].z},
                              {bv[0].w, bv[1].w, bv[2].w, bv[3].w}};
#pragma unroll
      for (int i = 0; i < 4; ++i) {
        short h[4], l[4];
#pragma unroll
        for (int j = 0; j < 4; ++j) split_bf16(bm[i][j], h[j], l[j]);
        *(short4v*)&Bh[nq + i][kb] = *(short4v*)&h[0];
        *(short4v*)&Bl[nq + i][kb] = *(short4v*)&l[0];
      }
    }
    __syncthreads();

    short8v afh[4], afl[4], bfh[4], bfl[4];
#pragma unroll
    for (int im = 0; im < 4; ++im) {
      afh[im] = *(const short8v*)&Ah[wr + im * 16 + fcol][kg * 8];
      afl[im] = *(const short8v*)&Al[wr + im * 16 + fcol][kg * 8];
    }
#pragma unroll
    for (int in = 0; in < 4; ++in) {
      bfh[in] = *(const short8v*)&Bh[wc + in * 16 + fcol][kg * 8];
      bfl[in] = *(const short8v*)&Bl[wc + in * 16 + fcol][kg * 8];
    }
#pragma unroll
    for (int im = 0; im < 4; ++im)
#pragma unroll
      for (int in = 0; in < 4; ++in) {
        acc[im][in] = __builtin_amdgcn_mfma_f32_16x16x32_bf16(
            afh[im], bfh[in], acc[im][in], 0, 0, 0);
        acc[im][in] = __builtin_amdgcn_mfma_f32_16x16x32_bf16(
            afh[im], bfl[in], acc[im][in], 0, 0, 0);
        acc[im][in] = __builtin_amdgcn_mfma_f32_16x16x32_bf16(
            afl[im], bfh[in], acc[im][in], 0, 0, 0);
      }
  }

#pragma unroll
  for (int in = 0; in < 4; ++in) {
    const int col = col0 + wc + in * 16 + fcol;
    const float bvx = bias[col];
#pragma unroll
    for (int im = 0; im < 4; ++im) {
      const int rbase = row0 + wr + im * 16 + kg * 4;
#pragma unroll
      for (int r = 0; r < 4; ++r)
        Cb[(size_t)(rbase + r) * 256 + col] = acc[im][in][r] + bvx;
    }
  }
}

extern "C" void kernel_launch(void* const* d_in, const int* in_sizes, int n_in,
                              void* d_out, int out_size, void* d_ws,
                              size_t ws_size, hipStream_t stream) {
  const float* features = (const float*)d_in[0];
  const float* fm       = (const float*)d_in[1];
  const float* W1 = (const float*)d_in[2];
  const float* b1 = (const float*)d_in[3];
  const float* W2 = (const float*)d_in[4];
  const float* b2 = (const float*)d_in[5];
  const float* W3 = (const float*)d_in[6];
  const float* b3 = (const float*)d_in[7];
  const float* Wl = (const float*)d_in[8];
  const float* bl = (const float*)d_in[9];
  float* out = (float*)d_out;

  // ws layout (44.0 MB):
  //   tbl      @ 0       .. 524KB   (513KB used)
  //   rowscale @ 576KB   .. 608KB   (32KB)
  //   counter  @ 640KB   (4B), worklist follows (512KB)
  //   adj_bin  @ 2.0MB   .. 10.4MB  (f32 8.4MB)
  //   corr64   @ 10.5MB  .. 27.3MB  (f64, dead after K2b)
  //   X        @ 10.5MB  .. 44.0MB  (f32, overwrites corr64 - safe)
  char* ws = (char*)d_ws;
  float* tbl        = (float*)ws;
  float* rowscale   = (float*)(ws + 576u * 1024u);
  uint32_t* counter = (uint32_t*)(ws + 640u * 1024u);
  uint32_t* worklist = counter + 16;  // 64B-aligned start
  float* adj_bin    = (float*)(ws + 2u * 1024u * 1024u);
  double* corr64    = (double*)(ws + 10800u * 1024u);
  float* X          = (float*)(ws + 10800u * 1024u);

  build_table_kernel<<<dim3(513), 256, 0, stream>>>(W1, b1, W2, b2, W3, b3,
                                                    tbl);
  init_counter_kernel<<<dim3(1), 1, 0, stream>>>(counter);
  corr_gemm64_kernel<<<dim3(4, 4, 32), 256, 0, stream>>>(fm, corr64);
  // ONE thread per adjacency element: 8192 blocks (round-9 bug was 16384).
  decide_fast_kernel<<<dim3(8192), 256, 0, stream>>>(corr64, tbl, adj_bin,
                                                     counter, worklist);
  decide_exact_kernel<<<dim3(64), 64, 0, stream>>>(corr64, counter, worklist,
                                                   W1, b1, W2, b2, W3, b3,
                                                   adj_bin);
  rowscale_kernel<<<dim3(2048), 256, 0, stream>>>(adj_bin, rowscale);
  // X[b,c] = rs * (adj_bin[b] @ F[b,c])
  gemm_binA_kernel<<<dim3(2, 2, 128), 256, 0, stream>>>(adj_bin, features,
                                                        rowscale, X);
  // out[b,c] = X[b,c] @ Wl + bl
  gemm_mfma_kernel<<<dim3(2, 2, 128), 256, 0, stream>>>(X, Wl, bl, out);
}

// Round 11
// 112.567 us; speedup vs baseline: 4.1842x; 1.0745x over previous
//
#include <hip/hip_runtime.h>
#include <stdint.h>

// ---------------------------------------------------------------------------
// B=32, C=4, S=256, L=256, Din=Dout=256
// Pipeline:
//   K0  build_table: dphi table (131073 nodes over [-128,128], mlp32 nodes)
//   Ki  init: zero worklist counter
//   K1  corr_gemm64: corr[b] = fm[b] @ fm[b]^T, f64 accumulate/store
//   K2f decide_fast: elementwise lerp+gumbel32 decision, |margin|>=4e-4
//       guard; pendings -> worklist, adj_bin in {0,1}
//   K2b decide_exact: ONE WAVE PER ITEM exact f64 resolve (same ops/order as
//       the validated mlp64 path; erf chain parallelized across lanes)
//   K2c rowscale: rs[row] = 1.0f / rowsum(adj_bin)
//   K3  gemm_binA: X[b,c] = rs * (adj_bin[b] @ F[b,c])   (exact-bf16 A, 2-term B)
//   K4  gemm_mfma: out = X @ Wl + bl                     (bf16x3, 3-term)
// threefry partitionable (jax key 42): bits(i) = o0^o1 of tf2x32((0,42),(0,i))
// ---------------------------------------------------------------------------

#define TBL_INTERVALS 131072
#define TBL_MIN -128.0f
#define TBL_SCALE 512.0f
#define WL_CAP 131072u

typedef __attribute__((ext_vector_type(8))) short short8v;
typedef __attribute__((ext_vector_type(4))) short short4v;
typedef __attribute__((ext_vector_type(4))) float float4v;

__device__ __forceinline__ void threefry2x32(uint32_t x0, uint32_t x1,
                                             uint32_t& o0, uint32_t& o1) {
  const uint32_t ks0 = 0u;
  const uint32_t ks1 = 42u;
  const uint32_t ks2 = 0x1BD11BDAu ^ ks0 ^ ks1;
  const uint32_t ks[3] = {ks0, ks1, ks2};
  const uint32_t rot[2][4] = {{13u, 15u, 26u, 6u}, {17u, 29u, 16u, 24u}};
  x0 += ks0;
  x1 += ks1;
#pragma unroll
  for (int i = 0; i < 5; ++i) {
#pragma unroll
    for (int j = 0; j < 4; ++j) {
      const uint32_t r = rot[i & 1][j];
      x0 += x1;
      x1 = (x1 << r) | (x1 >> (32u - r));
      x1 ^= x0;
    }
    x0 += ks[(i + 1) % 3];
    x1 += ks[(i + 2) % 3] + (uint32_t)(i + 1);
  }
  o0 = x0;
  o1 = x1;
}

__device__ __forceinline__ float uniform_at(uint32_t j) {
  uint32_t o0, o1;
  threefry2x32(0u, j, o0, o1);
  const uint32_t bits = o0 ^ o1;
  uint32_t fb = (bits >> 9) | 0x3F800000u;
  float frac = __uint_as_float(fb) - 1.0f;
  return fmaxf(frac + 1e-10f, 1e-10f);
}

__device__ __forceinline__ double gumbel64_at(uint32_t j) {
  double t = -log((double)uniform_at(j));
  return -log(t);
}

__device__ __forceinline__ float gumbel32_at(uint32_t j) {
  float t = -logf(uniform_at(j));
  return -logf(t);
}

__device__ __forceinline__ double gelu_d(double x) {
  return 0.5 * x * (1.0 + erf(x * 0.70710678118654752440));
}

__device__ __forceinline__ float gelu_f(float x) {
  return 0.5f * x * (1.0f + erff(x * 0.70710678f));
}

__device__ __forceinline__ float mlp32(float corr, const float* __restrict__ W1,
                                       const float* __restrict__ b1,
                                       const float* __restrict__ W2,
                                       const float* __restrict__ b2,
                                       const float* __restrict__ W3,
                                       const float* __restrict__ b3) {
  float h1[16];
#pragma unroll
  for (int u = 0; u < 16; ++u) h1[u] = gelu_f(fmaf(corr, W1[u], b1[u]));
  float h2[8];
#pragma unroll
  for (int v = 0; v < 8; ++v) {
    float x = b2[v];
#pragma unroll
    for (int u = 0; u < 16; ++u) x = fmaf(h1[u], W2[u * 8 + v], x);
    h2[v] = gelu_f(x);
  }
  float l0 = b3[0], l1 = b3[1];
#pragma unroll
  for (int v = 0; v < 8; ++v) {
    l0 = fmaf(h2[v], W3[v * 2 + 0], l0);
    l1 = fmaf(h2[v], W3[v * 2 + 1], l1);
  }
  return l0 - l1;
}

// RNE f32 -> bf16 split
__device__ __forceinline__ void split_bf16(float x, short& h, short& l) {
  uint32_t u = __float_as_uint(x);
  uint32_t hr = (u + 0x7FFFu + ((u >> 16) & 1u)) >> 16;
  float hf = __uint_as_float(hr << 16);
  float lo = x - hf;
  uint32_t v = __float_as_uint(lo);
  uint32_t lr = (v + 0x7FFFu + ((v >> 16) & 1u)) >> 16;
  h = (short)hr;
  l = (short)lr;
}

__device__ __forceinline__ short bf16_exact(float x) {
  // for values exactly representable in bf16 (0.0f / 1.0f)
  return (short)(__float_as_uint(x) >> 16);
}

// ---------------------------------------------------------------------------
__global__ __launch_bounds__(256) void build_table_kernel(
    const float* __restrict__ W1, const float* __restrict__ b1,
    const float* __restrict__ W2, const float* __restrict__ b2,
    const float* __restrict__ W3, const float* __restrict__ b3,
    float* __restrict__ tbl) {
  const int i = blockIdx.x * 256 + threadIdx.x;
  if (i > TBL_INTERVALS) return;
  const float x = TBL_MIN + (float)i * (1.0f / TBL_SCALE);
  tbl[i] = mlp32(x, W1, b1, W2, b2, W3, b3);
}

__global__ void init_counter_kernel(uint32_t* __restrict__ c) { c[0] = 0u; }

// ---------------------------------------------------------------------------
// K1: corr[b] = fm[b] @ fm[b]^T, f64 accumulate, f64 store.
// ---------------------------------------------------------------------------
__global__ __launch_bounds__(256) void corr_gemm64_kernel(
    const float* __restrict__ fm, double* __restrict__ corr) {
  const int b = blockIdx.z;
  const int row0 = blockIdx.y * 64;
  const int col0 = blockIdx.x * 64;
  const float* base = fm + (size_t)b * 65536;

  __shared__ float As[32][68];
  __shared__ float Bs[32][68];

  const int tid = threadIdx.x;
  const int tx = tid & 15;
  const int ty = tid >> 4;
  const int m = tid >> 2;
  const int c = (tid & 3) * 8;

  double acc[4][4];
#pragma unroll
  for (int i = 0; i < 4; ++i)
#pragma unroll
    for (int j = 0; j < 4; ++j) acc[i][j] = 0.0;

  for (int k0 = 0; k0 < 256; k0 += 32) {
    float4 v0 = *(const float4*)(base + (size_t)(row0 + m) * 256 + k0 + c);
    float4 v1 = *(const float4*)(base + (size_t)(row0 + m) * 256 + k0 + c + 4);
    float4 w0 = *(const float4*)(base + (size_t)(col0 + m) * 256 + k0 + c);
    float4 w1 = *(const float4*)(base + (size_t)(col0 + m) * 256 + k0 + c + 4);
    __syncthreads();
    As[c + 0][m] = v0.x; As[c + 1][m] = v0.y;
    As[c + 2][m] = v0.z; As[c + 3][m] = v0.w;
    As[c + 4][m] = v1.x; As[c + 5][m] = v1.y;
    As[c + 6][m] = v1.z; As[c + 7][m] = v1.w;
    Bs[c + 0][m] = w0.x; Bs[c + 1][m] = w0.y;
    Bs[c + 2][m] = w0.z; Bs[c + 3][m] = w0.w;
    Bs[c + 4][m] = w1.x; Bs[c + 5][m] = w1.y;
    Bs[c + 6][m] = w1.z; Bs[c + 7][m] = w1.w;
    __syncthreads();

#pragma unroll
    for (int kk = 0; kk < 32; ++kk) {
      float a[4], bv[4];
      *(float4*)a = *(const float4*)(&As[kk][ty * 4]);
      *(float4*)bv = *(const float4*)(&Bs[kk][tx * 4]);
      double ad[4], bd[4];
#pragma unroll
      for (int i = 0; i < 4; ++i) {
        ad[i] = (double)a[i];
        bd[i] = (double)bv[i];
      }
#pragma unroll
      for (int i = 0; i < 4; ++i)
#pragma unroll
        for (int j = 0; j < 4; ++j) acc[i][j] = fma(ad[i], bd[j], acc[i][j]);
    }
  }

  double* Cb = corr + (size_t)b * 65536;
#pragma unroll
  for (int i = 0; i < 4; ++i) {
    const int row = row0 + ty * 4 + i;
    double2 o0 = {acc[i][0], acc[i][1]};
    double2 o1 = {acc[i][2], acc[i][3]};
    *(double2*)(Cb + (size_t)row * 256 + col0 + tx * 4) = o0;
    *(double2*)(Cb + (size_t)row * 256 + col0 + tx * 4 + 2) = o1;
  }
}

// ---------------------------------------------------------------------------
// K2f: lean elementwise fast decision. One thread per adjacency ELEMENT.
// grid 8192 x 256 = 2,097,152 threads (= B*S*S).
// ---------------------------------------------------------------------------
__global__ __launch_bounds__(256) void decide_fast_kernel(
    const double* __restrict__ corr, const float* __restrict__ tbl,
    float* __restrict__ adj_bin, uint32_t* __restrict__ counter,
    uint32_t* __restrict__ worklist) {
  const uint32_t flat = blockIdx.x * 256u + threadIdx.x;  // < 2,097,152
  const int t = flat & 255;
  const int s = (flat >> 8) & 255;

  float a = 1.0f;
  bool pend = false;
  if (t != s) {
    const float cf = (float)corr[flat];
    if (fabsf(cf) >= 127.0f) {
      pend = true;
      a = 0.0f;
    } else {
      const float xf = (cf - TBL_MIN) * TBL_SCALE;
      const int i = (int)xf;
      const float fr = xf - (float)i;
      const float t0v = tbl[i];
      const float t1v = tbl[i + 1];
      const float dphi = fmaf(fr, t1v - t0v, t0v);

      const float g0 = gumbel32_at(2u * flat);
      const float g1 = gumbel32_at(2u * flat + 1u);
      const float d = dphi - (g1 - g0);
      if (fabsf(d) >= 4e-4f) {
        a = (d >= 0.0f) ? 1.0f : 0.0f;
      } else {
        pend = true;
        a = 0.0f;
      }
    }
  }
  if (pend) {
    const uint32_t idx = atomicAdd(counter, 1u);
    if (idx < WL_CAP) worklist[idx] = flat;
  }
  adj_bin[flat] = a;
}

// ---------------------------------------------------------------------------
// K2b: exact f64 resolve, ONE WAVE PER ITEM. Same expressions and
// accumulation order as the validated mlp64 path; h1/h2 erf chains run
// on parallel lanes, operands moved by shfl -> serial call chain is
// erf -> erf (+2 logs overlapped) instead of 24 erf + 4 log.
// grid 2048 x 256 = 8192 waves, wave-stride over worklist.
// ---------------------------------------------------------------------------
__global__ __launch_bounds__(256) void decide_exact_kernel(
    const double* __restrict__ corr, const uint32_t* __restrict__ counter,
    const uint32_t* __restrict__ worklist,
    const float* __restrict__ W1, const float* __restrict__ b1,
    const float* __restrict__ W2, const float* __restrict__ b2,
    const float* __restrict__ W3, const float* __restrict__ b3,
    float* __restrict__ adj_bin) {
  const uint32_t n = min(counter[0], WL_CAP);
  const uint32_t waveId = (blockIdx.x * 256u + threadIdx.x) >> 6;
  const uint32_t nWaves = (gridDim.x * 256u) >> 6;
  const int lane = threadIdx.x & 63;

  for (uint32_t it = waveId; it < n; it += nWaves) {
    const uint32_t flat = worklist[it];
    const double acc = corr[flat];

    // gumbel chain (independent of the MLP chain -> overlaps):
    // lane&1 selects G0/G1; same gumbel64_at as validated path.
    const double ga = gumbel64_at(2u * flat + (uint32_t)(lane & 1));

    // stage 1: h1[u] on lanes (u = lane & 15); identical expression to mlp64
    const int u = lane & 15;
    const double h1 = gelu_d(acc * (double)W1[u] + (double)b1[u]);

    // stage 2: h2[v] on lanes (v = lane & 7); same sequential u-order
    const int v = lane & 7;
    double s = (double)b2[v];
#pragma unroll
    for (int uu = 0; uu < 16; ++uu) {
      const double h1u = __shfl(h1, uu);
      s += h1u * (double)W2[uu * 8 + v];
    }
    const double h2 = gelu_d(s);

    // stage 3: l0/l1, same sequential v-order as mlp64
    double l0 = (double)b3[0], l1 = (double)b3[1];
#pragma unroll
    for (int vv = 0; vv < 8; ++vv) {
      const double h2v = __shfl(h2, vv);
      l0 += h2v * (double)W3[vv * 2 + 0];
      l1 += h2v * (double)W3[vv * 2 + 1];
    }

    const double G0 = __shfl(ga, 0);
    const double G1 = __shfl(ga, 1);
    if (lane == 0) adj_bin[flat] = (l0 + G0 >= l1 + G1) ? 1.0f : 0.0f;
  }
}

// ---------------------------------------------------------------------------
// K2c: rowscale. One wave per row; grid 2048 x 256.
// ---------------------------------------------------------------------------
__global__ __launch_bounds__(256) void rowscale_kernel(
    const float* __restrict__ adj_bin, float* __restrict__ rs) {
  const int row = blockIdx.x * 4 + (threadIdx.x >> 6);
  const int lane = threadIdx.x & 63;
  float4 v = ((const float4*)(adj_bin + (size_t)row * 256))[lane];
  float sum = v.x + v.y + v.z + v.w;
#pragma unroll
  for (int off = 32; off; off >>= 1) sum += __shfl_xor(sum, off);
  if (lane == 0) rs[row] = 1.0f / sum;
}

// ---------------------------------------------------------------------------
// K3: X[b,c] = rs * (adj_bin[b] @ F[b,c]). A is exact-bf16 binary (1 term),
// B split hi+lo (2 terms) -> 32 MFMA / K-step. Epilogue row-scale.
// ---------------------------------------------------------------------------
__global__ __launch_bounds__(256) void gemm_binA_kernel(
    const float* __restrict__ A, const float* __restrict__ B,
    const float* __restrict__ rs, float* __restrict__ C) {
  const int z = blockIdx.z;
  const float* Ab = A + (size_t)(z / 4) * 65536;
  const float* Bb = B + (size_t)z * 65536;
  const float* rsb = rs + (size_t)(z / 4) * 256;
  float* Cb = C + (size_t)z * 65536;

  const int row0 = blockIdx.y * 128;
  const int col0 = blockIdx.x * 128;

  __shared__ short Ah[128][40];
  __shared__ short Bh[128][40];  // transposed: [n][k]
  __shared__ short Bl[128][40];

  const int tid = threadIdx.x;
  const int w = tid >> 6;
  const int wr = (w >> 1) * 64;
  const int wc = (w & 1) * 64;
  const int lane = tid & 63;
  const int fcol = lane & 15;
  const int kg = lane >> 4;

  const int am = tid >> 1;
  const int ak = (tid & 1) * 16;
  const int nq = (tid & 31) * 4;
  const int kb = (tid >> 5) * 4;

  float4v acc[4][4];
#pragma unroll
  for (int i = 0; i < 4; ++i)
#pragma unroll
    for (int j = 0; j < 4; ++j) acc[i][j] = (float4v)(0.0f);

  for (int k0 = 0; k0 < 256; k0 += 32) {
    float4 av[4];
#pragma unroll
    for (int q = 0; q < 4; ++q)
      av[q] = *(const float4*)(Ab + (size_t)(row0 + am) * 256 + k0 + ak + q * 4);
    float4 bv[4];
#pragma unroll
    for (int j = 0; j < 4; ++j)
      bv[j] = *(const float4*)(Bb + (size_t)(k0 + kb + j) * 256 + col0 + nq);

    __syncthreads();

    {
      short h[16];
#pragma unroll
      for (int q = 0; q < 4; ++q) {
        h[q * 4 + 0] = bf16_exact(av[q].x);
        h[q * 4 + 1] = bf16_exact(av[q].y);
        h[q * 4 + 2] = bf16_exact(av[q].z);
        h[q * 4 + 3] = bf16_exact(av[q].w);
      }
      *(short8v*)&Ah[am][ak] = *(short8v*)&h[0];
      *(short8v*)&Ah[am][ak + 8] = *(short8v*)&h[8];
    }
    {
      const float bm[4][4] = {{bv[0].x, bv[1].x, bv[2].x, bv[3].x},
                              {bv[0].y, bv[1].y, bv[2].y, bv[3].y},
                              {bv[0].z, bv[1].z, bv[2].z, bv[3].z},
                              {bv[0].w, bv[1].w, bv[2].w, bv[3].w}};
#pragma unroll
      for (int i = 0; i < 4; ++i) {
        short h[4], l[4];
#pragma unroll
        for (int j = 0; j < 4; ++j) split_bf16(bm[i][j], h[j], l[j]);
        *(short4v*)&Bh[nq + i][kb] = *(short4v*)&h[0];
        *(short4v*)&Bl[nq + i][kb] = *(short4v*)&l[0];
      }
    }
    __syncthreads();

    short8v afh[4], bfh[4], bfl[4];
#pragma unroll
    for (int im = 0; im < 4; ++im)
      afh[im] = *(const short8v*)&Ah[wr + im * 16 + fcol][kg * 8];
#pragma unroll
    for (int in = 0; in < 4; ++in) {
      bfh[in] = *(const short8v*)&Bh[wc + in * 16 + fcol][kg * 8];
      bfl[in] = *(const short8v*)&Bl[wc + in * 16 + fcol][kg * 8];
    }
#pragma unroll
    for (int im = 0; im < 4; ++im)
#pragma unroll
      for (int in = 0; in < 4; ++in) {
        acc[im][in] = __builtin_amdgcn_mfma_f32_16x16x32_bf16(
            afh[im], bfh[in], acc[im][in], 0, 0, 0);
        acc[im][in] = __builtin_amdgcn_mfma_f32_16x16x32_bf16(
            afh[im], bfl[in], acc[im][in], 0, 0, 0);
      }
  }

#pragma unroll
  for (int im = 0; im < 4; ++im) {
    const int rbase = row0 + wr + im * 16 + kg * 4;
    float rsv[4];
#pragma unroll
    for (int r = 0; r < 4; ++r) rsv[r] = rsb[rbase + r];
#pragma unroll
    for (int in = 0; in < 4; ++in) {
      const int col = col0 + wc + in * 16 + fcol;
#pragma unroll
      for (int r = 0; r < 4; ++r)
        Cb[(size_t)(rbase + r) * 256 + col] = acc[im][in][r] * rsv[r];
    }
  }
}

// ---------------------------------------------------------------------------
// K4: out = X @ Wl + bl. bf16x3 (3-term) MFMA.
// ---------------------------------------------------------------------------
__global__ __launch_bounds__(256) void gemm_mfma_kernel(
    const float* __restrict__ A, const float* __restrict__ B,
    const float* __restrict__ bias, float* __restrict__ C) {
  const int z = blockIdx.z;
  const float* Ab = A + (size_t)z * 65536;
  const float* Bb = B;  // shared Wl
  float* Cb = C + (size_t)z * 65536;

  const int row0 = blockIdx.y * 128;
  const int col0 = blockIdx.x * 128;

  __shared__ short Ah[128][40];
  __shared__ short Al[128][40];
  __shared__ short Bh[128][40];
  __shared__ short Bl[128][40];

  const int tid = threadIdx.x;
  const int w = tid >> 6;
  const int wr = (w >> 1) * 64;
  const int wc = (w & 1) * 64;
  const int lane = tid & 63;
  const int fcol = lane & 15;
  const int kg = lane >> 4;

  const int am = tid >> 1;
  const int ak = (tid & 1) * 16;
  const int nq = (tid & 31) * 4;
  const int kb = (tid >> 5) * 4;

  float4v acc[4][4];
#pragma unroll
  for (int i = 0; i < 4; ++i)
#pragma unroll
    for (int j = 0; j < 4; ++j) acc[i][j] = (float4v)(0.0f);

  for (int k0 = 0; k0 < 256; k0 += 32) {
    float4 av[4];
#pragma unroll
    for (int q = 0; q < 4; ++q)
      av[q] = *(const float4*)(Ab + (size_t)(row0 + am) * 256 + k0 + ak + q * 4);
    float4 bv[4];
#pragma unroll
    for (int j = 0; j < 4; ++j)
      bv[j] = *(const float4*)(Bb + (size_t)(k0 + kb + j) * 256 + col0 + nq);

    __syncthreads();

    {
      short h[16], l[16];
#pragma unroll
      for (int q = 0; q < 4; ++q) {
        split_bf16(av[q].x, h[q * 4 + 0], l[q * 4 + 0]);
        split_bf16(av[q].y, h[q * 4 + 1], l[q * 4 + 1]);
        split_bf16(av[q].z, h[q * 4 + 2], l[q * 4 + 2]);
        split_bf16(av[q].w, h[q * 4 + 3], l[q * 4 + 3]);
      }
      *(short8v*)&Ah[am][ak] = *(short8v*)&h[0];
      *(short8v*)&Ah[am][ak + 8] = *(short8v*)&h[8];
      *(short8v*)&Al[am][ak] = *(short8v*)&l[0];
      *(short8v*)&Al[am][ak + 8] = *(short8v*)&l[8];
    }
    {
      const float bm[4][4] = {{bv[0].x, bv[1].x, bv[2].x, bv[3].x},
                              {bv[0].y, bv[1].y, bv[2].y, bv[3].y},
                              {bv[0].z, bv[1].z, bv[2].z, bv[3].z},
                              {bv[0].w, bv[1].w, bv[2].w, bv[3].w}};
#pragma unroll
      for (int i = 0; i < 4; ++i) {
        short h[4], l[4];
#pragma unroll
        for (int j = 0; j < 4; ++j) split_bf16(bm[i][j], h[j], l[j]);
        *(short4v*)&Bh[nq + i][kb] = *(short4v*)&h[0];
        *(short4v*)&Bl[nq + i][kb] = *(short4v*)&l[0];
      }
    }
    __syncthreads();

    short8v afh[4], afl[4], bfh[4], bfl[4];
#pragma unroll
    for (int im = 0; im < 4; ++im) {
      afh[im] = *(const short8v*)&Ah[wr + im * 16 + fcol][kg * 8];
      afl[im] = *(const short8v*)&Al[wr + im * 16 + fcol][kg * 8];
    }
#pragma unroll
    for (int in = 0; in < 4; ++in) {
      bfh[in] = *(const short8v*)&Bh[wc + in * 16 + fcol][kg * 8];
      bfl[in] = *(const short8v*)&Bl[wc + in * 16 + fcol][kg * 8];
    }
#pragma unroll
    for (int im = 0; im < 4; ++im)
#pragma unroll
      for (int in = 0; in < 4; ++in) {
        acc[im][in] = __builtin_amdgcn_mfma_f32_16x16x32_bf16(
            afh[im], bfh[in], acc[im][in], 0, 0, 0);
        acc[im][in] = __builtin_amdgcn_mfma_f32_16x16x32_bf16(
            afh[im], bfl[in], acc[im][in], 0, 0, 0);
        acc[im][in] = __builtin_amdgcn_mfma_f32_16x16x32_bf16(
            afl[im], bfh[in], acc[im][in], 0, 0, 0);
      }
  }

#pragma unroll
  for (int in = 0; in < 4; ++in) {
    const int col = col0 + wc + in * 16 + fcol;
    const float bvx = bias[col];
#pragma unroll
    for (int im = 0; im < 4; ++im) {
      const int rbase = row0 + wr + im * 16 + kg * 4;
#pragma unroll
      for (int r = 0; r < 4; ++r)
        Cb[(size_t)(rbase + r) * 256 + col] = acc[im][in][r] + bvx;
    }
  }
}

extern "C" void kernel_launch(void* const* d_in, const int* in_sizes, int n_in,
                              void* d_out, int out_size, void* d_ws,
                              size_t ws_size, hipStream_t stream) {
  const float* features = (const float*)d_in[0];
  const float* fm       = (const float*)d_in[1];
  const float* W1 = (const float*)d_in[2];
  const float* b1 = (const float*)d_in[3];
  const float* W2 = (const float*)d_in[4];
  const float* b2 = (const float*)d_in[5];
  const float* W3 = (const float*)d_in[6];
  const float* b3 = (const float*)d_in[7];
  const float* Wl = (const float*)d_in[8];
  const float* bl = (const float*)d_in[9];
  float* out = (float*)d_out;

  // ws layout (44.0 MB):
  //   tbl      @ 0       .. 524KB   (513KB used)
  //   rowscale @ 576KB   .. 608KB   (32KB)
  //   counter  @ 640KB   (4B), worklist follows (512KB)
  //   adj_bin  @ 2.0MB   .. 10.4MB  (f32 8.4MB)
  //   corr64   @ 10.5MB  .. 27.3MB  (f64, dead after K2b)
  //   X        @ 10.5MB  .. 44.0MB  (f32, overwrites corr64 - safe)
  char* ws = (char*)d_ws;
  float* tbl        = (float*)ws;
  float* rowscale   = (float*)(ws + 576u * 1024u);
  uint32_t* counter = (uint32_t*)(ws + 640u * 1024u);
  uint32_t* worklist = counter + 16;  // 64B-aligned start
  float* adj_bin    = (float*)(ws + 2u * 1024u * 1024u);
  double* corr64    = (double*)(ws + 10800u * 1024u);
  float* X          = (float*)(ws + 10800u * 1024u);

  build_table_kernel<<<dim3(513), 256, 0, stream>>>(W1, b1, W2, b2, W3, b3,
                                                    tbl);
  init_counter_kernel<<<dim3(1), 1, 0, stream>>>(counter);
  corr_gemm64_kernel<<<dim3(4, 4, 32), 256, 0, stream>>>(fm, corr64);
  decide_fast_kernel<<<dim3(8192), 256, 0, stream>>>(corr64, tbl, adj_bin,
                                                     counter, worklist);
  // one wave per pending item
  decide_exact_kernel<<<dim3(2048), 256, 0, stream>>>(corr64, counter,
                                                      worklist, W1, b1, W2, b2,
                                                      W3, b3, adj_bin);
  rowscale_kernel<<<dim3(2048), 256, 0, stream>>>(adj_bin, rowscale);
  // X[b,c] = rs * (adj_bin[b] @ F[b,c])
  gemm_binA_kernel<<<dim3(2, 2, 128), 256, 0, stream>>>(adj_bin, features,
                                                        rowscale, X);
  // out[b,c] = X[b,c] @ Wl + bl
  gemm_mfma_kernel<<<dim3(2, 2, 128), 256, 0, stream>>>(X, Wl, bl, out);
}

// Round 12
// 97.179 us; speedup vs baseline: 4.8467x; 1.1583x over previous
//
#include <hip/hip_runtime.h>
#include <stdint.h>

// ---------------------------------------------------------------------------
// B=32, C=4, S=256, L=256, Din=Dout=256
// Pipeline:
//   K0  build_table: dphi table (131073 nodes over [-128,128], mlp32 nodes)
//   Ki  init: zero worklist counter
//   K1  corr_mfma: corr[b] = fm[b] @ fm[b]^T, 4-term bf16-split MFMA, f32 out
//       (bf16 products exact in f32; err = 2^-16 split residuals + f32 accum)
//   K2f decide_fast: elementwise lerp+gumbel32 decision, DYNAMIC guard
//       thr = 4e-4 + slope*6e-4 (slope from table diff); pendings -> worklist
//   K2b decide_exact: ONE WAVE PER ITEM: exact f64 dot from fm (coalesced,
//       butterfly-reduced) + lane-parallel mlp64 + gumbel64 (round-11 path)
//   K2c rowscale: rs[row] = 1.0f / rowsum(adj_bin)
//   K3  gemm_binA: X[b,c] = rs * (adj_bin[b] @ F[b,c])  (exact-bf16 A, 2-term B)
//   K4  gemm_mfma: out = X @ Wl + bl                    (bf16x3, 3-term)
// threefry partitionable (jax key 42): bits(i) = o0^o1 of tf2x32((0,42),(0,i))
// ---------------------------------------------------------------------------

#define TBL_INTERVALS 131072
#define TBL_MIN -128.0f
#define TBL_SCALE 512.0f
#define WL_CAP 131072u

typedef __attribute__((ext_vector_type(8))) short short8v;
typedef __attribute__((ext_vector_type(4))) short short4v;
typedef __attribute__((ext_vector_type(4))) float float4v;

__device__ __forceinline__ void threefry2x32(uint32_t x0, uint32_t x1,
                                             uint32_t& o0, uint32_t& o1) {
  const uint32_t ks0 = 0u;
  const uint32_t ks1 = 42u;
  const uint32_t ks2 = 0x1BD11BDAu ^ ks0 ^ ks1;
  const uint32_t ks[3] = {ks0, ks1, ks2};
  const uint32_t rot[2][4] = {{13u, 15u, 26u, 6u}, {17u, 29u, 16u, 24u}};
  x0 += ks0;
  x1 += ks1;
#pragma unroll
  for (int i = 0; i < 5; ++i) {
#pragma unroll
    for (int j = 0; j < 4; ++j) {
      const uint32_t r = rot[i & 1][j];
      x0 += x1;
      x1 = (x1 << r) | (x1 >> (32u - r));
      x1 ^= x0;
    }
    x0 += ks[(i + 1) % 3];
    x1 += ks[(i + 2) % 3] + (uint32_t)(i + 1);
  }
  o0 = x0;
  o1 = x1;
}

__device__ __forceinline__ float uniform_at(uint32_t j) {
  uint32_t o0, o1;
  threefry2x32(0u, j, o0, o1);
  const uint32_t bits = o0 ^ o1;
  uint32_t fb = (bits >> 9) | 0x3F800000u;
  float frac = __uint_as_float(fb) - 1.0f;
  return fmaxf(frac + 1e-10f, 1e-10f);
}

__device__ __forceinline__ double gumbel64_at(uint32_t j) {
  double t = -log((double)uniform_at(j));
  return -log(t);
}

__device__ __forceinline__ float gumbel32_at(uint32_t j) {
  float t = -logf(uniform_at(j));
  return -logf(t);
}

__device__ __forceinline__ double gelu_d(double x) {
  return 0.5 * x * (1.0 + erf(x * 0.70710678118654752440));
}

__device__ __forceinline__ float gelu_f(float x) {
  return 0.5f * x * (1.0f + erff(x * 0.70710678f));
}

__device__ __forceinline__ float mlp32(float corr, const float* __restrict__ W1,
                                       const float* __restrict__ b1,
                                       const float* __restrict__ W2,
                                       const float* __restrict__ b2,
                                       const float* __restrict__ W3,
                                       const float* __restrict__ b3) {
  float h1[16];
#pragma unroll
  for (int u = 0; u < 16; ++u) h1[u] = gelu_f(fmaf(corr, W1[u], b1[u]));
  float h2[8];
#pragma unroll
  for (int v = 0; v < 8; ++v) {
    float x = b2[v];
#pragma unroll
    for (int u = 0; u < 16; ++u) x = fmaf(h1[u], W2[u * 8 + v], x);
    h2[v] = gelu_f(x);
  }
  float l0 = b3[0], l1 = b3[1];
#pragma unroll
  for (int v = 0; v < 8; ++v) {
    l0 = fmaf(h2[v], W3[v * 2 + 0], l0);
    l1 = fmaf(h2[v], W3[v * 2 + 1], l1);
  }
  return l0 - l1;
}

// RNE f32 -> bf16 split
__device__ __forceinline__ void split_bf16(float x, short& h, short& l) {
  uint32_t u = __float_as_uint(x);
  uint32_t hr = (u + 0x7FFFu + ((u >> 16) & 1u)) >> 16;
  float hf = __uint_as_float(hr << 16);
  float lo = x - hf;
  uint32_t v = __float_as_uint(lo);
  uint32_t lr = (v + 0x7FFFu + ((v >> 16) & 1u)) >> 16;
  h = (short)hr;
  l = (short)lr;
}

__device__ __forceinline__ short bf16_exact(float x) {
  // for values exactly representable in bf16 (0.0f / 1.0f)
  return (short)(__float_as_uint(x) >> 16);
}

// ---------------------------------------------------------------------------
__global__ __launch_bounds__(256) void build_table_kernel(
    const float* __restrict__ W1, const float* __restrict__ b1,
    const float* __restrict__ W2, const float* __restrict__ b2,
    const float* __restrict__ W3, const float* __restrict__ b3,
    float* __restrict__ tbl) {
  const int i = blockIdx.x * 256 + threadIdx.x;
  if (i > TBL_INTERVALS) return;
  const float x = TBL_MIN + (float)i * (1.0f / TBL_SCALE);
  tbl[i] = mlp32(x, W1, b1, W2, b2, W3, b3);
}

__global__ void init_counter_kernel(uint32_t* __restrict__ c) { c[0] = 0u; }

// ---------------------------------------------------------------------------
// K1: corr[b] = fm[b] @ fm[b]^T via 4-term bf16-split MFMA, f32 output.
// 128x128 tile, BK=32, 4 waves x (64x64). grid (2,2,32).
// Both tiles are row-reads of fm (B-tile = rows col0+n) -> coalesced.
// ---------------------------------------------------------------------------
__global__ __launch_bounds__(256) void corr_mfma_kernel(
    const float* __restrict__ fm, float* __restrict__ corr) {
  const int b = blockIdx.z;
  const float* base = fm + (size_t)b * 65536;
  const int row0 = blockIdx.y * 128;
  const int col0 = blockIdx.x * 128;

  __shared__ short Ah[128][40];
  __shared__ short Al[128][40];
  __shared__ short Bh[128][40];  // [n][k]
  __shared__ short Bl[128][40];

  const int tid = threadIdx.x;
  const int w = tid >> 6;
  const int wr = (w >> 1) * 64;
  const int wc = (w & 1) * 64;
  const int lane = tid & 63;
  const int fcol = lane & 15;
  const int kg = lane >> 4;

  const int am = tid >> 1;
  const int ak = (tid & 1) * 16;

  float4v acc[4][4];
#pragma unroll
  for (int i = 0; i < 4; ++i)
#pragma unroll
    for (int j = 0; j < 4; ++j) acc[i][j] = (float4v)(0.0f);

  for (int k0 = 0; k0 < 256; k0 += 32) {
    float4 av[4], bv[4];
#pragma unroll
    for (int q = 0; q < 4; ++q) {
      av[q] = *(const float4*)(base + (size_t)(row0 + am) * 256 + k0 + ak + q * 4);
      bv[q] = *(const float4*)(base + (size_t)(col0 + am) * 256 + k0 + ak + q * 4);
    }

    __syncthreads();

    {
      short h[16], l[16];
#pragma unroll
      for (int q = 0; q < 4; ++q) {
        split_bf16(av[q].x, h[q * 4 + 0], l[q * 4 + 0]);
        split_bf16(av[q].y, h[q * 4 + 1], l[q * 4 + 1]);
        split_bf16(av[q].z, h[q * 4 + 2], l[q * 4 + 2]);
        split_bf16(av[q].w, h[q * 4 + 3], l[q * 4 + 3]);
      }
      *(short8v*)&Ah[am][ak] = *(short8v*)&h[0];
      *(short8v*)&Ah[am][ak + 8] = *(short8v*)&h[8];
      *(short8v*)&Al[am][ak] = *(short8v*)&l[0];
      *(short8v*)&Al[am][ak + 8] = *(short8v*)&l[8];
#pragma unroll
      for (int q = 0; q < 4; ++q) {
        split_bf16(bv[q].x, h[q * 4 + 0], l[q * 4 + 0]);
        split_bf16(bv[q].y, h[q * 4 + 1], l[q * 4 + 1]);
        split_bf16(bv[q].z, h[q * 4 + 2], l[q * 4 + 2]);
        split_bf16(bv[q].w, h[q * 4 + 3], l[q * 4 + 3]);
      }
      *(short8v*)&Bh[am][ak] = *(short8v*)&h[0];
      *(short8v*)&Bh[am][ak + 8] = *(short8v*)&h[8];
      *(short8v*)&Bl[am][ak] = *(short8v*)&l[0];
      *(short8v*)&Bl[am][ak + 8] = *(short8v*)&l[8];
    }
    __syncthreads();

    short8v afh[4], afl[4], bfh[4], bfl[4];
#pragma unroll
    for (int im = 0; im < 4; ++im) {
      afh[im] = *(const short8v*)&Ah[wr + im * 16 + fcol][kg * 8];
      afl[im] = *(const short8v*)&Al[wr + im * 16 + fcol][kg * 8];
    }
#pragma unroll
    for (int in = 0; in < 4; ++in) {
      bfh[in] = *(const short8v*)&Bh[wc + in * 16 + fcol][kg * 8];
      bfl[in] = *(const short8v*)&Bl[wc + in * 16 + fcol][kg * 8];
    }
#pragma unroll
    for (int im = 0; im < 4; ++im)
#pragma unroll
      for (int in = 0; in < 4; ++in) {
        acc[im][in] = __builtin_amdgcn_mfma_f32_16x16x32_bf16(
            afh[im], bfh[in], acc[im][in], 0, 0, 0);
        acc[im][in] = __builtin_amdgcn_mfma_f32_16x16x32_bf16(
            afh[im], bfl[in], acc[im][in], 0, 0, 0);
        acc[im][in] = __builtin_amdgcn_mfma_f32_16x16x32_bf16(
            afl[im], bfh[in], acc[im][in], 0, 0, 0);
        acc[im][in] = __builtin_amdgcn_mfma_f32_16x16x32_bf16(
            afl[im], bfl[in], acc[im][in], 0, 0, 0);
      }
  }

  float* Cb = corr + (size_t)b * 65536;
#pragma unroll
  for (int in = 0; in < 4; ++in) {
    const int col = col0 + wc + in * 16 + fcol;
#pragma unroll
    for (int im = 0; im < 4; ++im) {
      const int rbase = row0 + wr + im * 16 + kg * 4;
#pragma unroll
      for (int r = 0; r < 4; ++r)
        Cb[(size_t)(rbase + r) * 256 + col] = acc[im][in][r];
    }
  }
}

// ---------------------------------------------------------------------------
// K2f: lean elementwise fast decision with DYNAMIC (slope-aware) guard.
// thr = 4e-4 + |d_tbl| * 512 * 6e-4.  grid 8192 x 256.
// ---------------------------------------------------------------------------
__global__ __launch_bounds__(256) void decide_fast_kernel(
    const float* __restrict__ corr, const float* __restrict__ tbl,
    float* __restrict__ adj_bin, uint32_t* __restrict__ counter,
    uint32_t* __restrict__ worklist) {
  const uint32_t flat = blockIdx.x * 256u + threadIdx.x;  // < 2,097,152
  const int t = flat & 255;
  const int s = (flat >> 8) & 255;

  float a = 1.0f;
  bool pend = false;
  if (t != s) {
    const float cf = corr[flat];
    if (fabsf(cf) >= 127.0f) {
      pend = true;
      a = 0.0f;
    } else {
      const float xf = (cf - TBL_MIN) * TBL_SCALE;
      const int i = (int)xf;
      const float fr = xf - (float)i;
      const float t0v = tbl[i];
      const float t1v = tbl[i + 1];
      const float dt = t1v - t0v;
      const float dphi = fmaf(fr, dt, t0v);

      const float g0 = gumbel32_at(2u * flat);
      const float g1 = gumbel32_at(2u * flat + 1u);
      const float d = dphi - (g1 - g0);
      // base 4e-4 (lerp + node + gumbel32) + slope * 6e-4 (corr 6-sigma err)
      const float thr = fmaf(fabsf(dt), 0.3072f, 4e-4f);
      if (fabsf(d) >= thr) {
        a = (d >= 0.0f) ? 1.0f : 0.0f;
      } else {
        pend = true;
        a = 0.0f;
      }
    }
  }
  if (pend) {
    const uint32_t idx = atomicAdd(counter, 1u);
    if (idx < WL_CAP) worklist[idx] = flat;
  }
  adj_bin[flat] = a;
}

// ---------------------------------------------------------------------------
// K2b: exact f64 resolve, ONE WAVE PER ITEM. Exact f64 dot recomputed from
// fm (coalesced lane-strided loads, deterministic butterfly reduce), then
// the round-11 lane-parallel mlp64 + gumbel64. grid 2048 x 256.
// ---------------------------------------------------------------------------
__global__ __launch_bounds__(256) void decide_exact_kernel(
    const float* __restrict__ fm, const uint32_t* __restrict__ counter,
    const uint32_t* __restrict__ worklist,
    const float* __restrict__ W1, const float* __restrict__ b1,
    const float* __restrict__ W2, const float* __restrict__ b2,
    const float* __restrict__ W3, const float* __restrict__ b3,
    float* __restrict__ adj_bin) {
  const uint32_t n = min(counter[0], WL_CAP);
  const uint32_t waveId = (blockIdx.x * 256u + threadIdx.x) >> 6;
  const uint32_t nWaves = (gridDim.x * 256u) >> 6;
  const int lane = threadIdx.x & 63;

  for (uint32_t it = waveId; it < n; it += nWaves) {
    const uint32_t flat = worklist[it];
    const uint32_t bb = flat >> 16;
    const uint32_t ss = (flat >> 8) & 255u;
    const uint32_t tt = flat & 255u;

    // exact f64 dot: lane k-slices, coalesced; butterfly reduce (fixed order)
    const float* S = fm + ((size_t)bb * 256 + ss) * 256;
    const float* T = fm + ((size_t)bb * 256 + tt) * 256;
    double p = 0.0;
#pragma unroll
    for (int q = 0; q < 4; ++q) {
      const int k = lane + q * 64;
      p += (double)S[k] * (double)T[k];
    }
#pragma unroll
    for (int off = 32; off; off >>= 1) p += __shfl_xor(p, off);
    const double acc = p;

    // gumbel chain (overlaps MLP chain): lane&1 selects G0/G1
    const double ga = gumbel64_at(2u * flat + (uint32_t)(lane & 1));

    // h1 on lanes (u = lane & 15)
    const int u = lane & 15;
    const double h1 = gelu_d(acc * (double)W1[u] + (double)b1[u]);

    // h2 on lanes (v = lane & 7), same sequential u-order as mlp64
    const int v = lane & 7;
    double sv = (double)b2[v];
#pragma unroll
    for (int uu = 0; uu < 16; ++uu) {
      const double h1u = __shfl(h1, uu);
      sv += h1u * (double)W2[uu * 8 + v];
    }
    const double h2 = gelu_d(sv);

    // l0/l1, same sequential v-order
    double l0 = (double)b3[0], l1 = (double)b3[1];
#pragma unroll
    for (int vv = 0; vv < 8; ++vv) {
      const double h2v = __shfl(h2, vv);
      l0 += h2v * (double)W3[vv * 2 + 0];
      l1 += h2v * (double)W3[vv * 2 + 1];
    }

    const double G0 = __shfl(ga, 0);
    const double G1 = __shfl(ga, 1);
    if (lane == 0) adj_bin[flat] = (l0 + G0 >= l1 + G1) ? 1.0f : 0.0f;
  }
}

// ---------------------------------------------------------------------------
// K2c: rowscale. One wave per row; grid 2048 x 256.
// ---------------------------------------------------------------------------
__global__ __launch_bounds__(256) void rowscale_kernel(
    const float* __restrict__ adj_bin, float* __restrict__ rs) {
  const int row = blockIdx.x * 4 + (threadIdx.x >> 6);
  const int lane = threadIdx.x & 63;
  float4 v = ((const float4*)(adj_bin + (size_t)row * 256))[lane];
  float sum = v.x + v.y + v.z + v.w;
#pragma unroll
  for (int off = 32; off; off >>= 1) sum += __shfl_xor(sum, off);
  if (lane == 0) rs[row] = 1.0f / sum;
}

// ---------------------------------------------------------------------------
// K3: X[b,c] = rs * (adj_bin[b] @ F[b,c]). A exact-bf16 binary, 2-term B.
// ---------------------------------------------------------------------------
__global__ __launch_bounds__(256) void gemm_binA_kernel(
    const float* __restrict__ A, const float* __restrict__ B,
    const float* __restrict__ rs, float* __restrict__ C) {
  const int z = blockIdx.z;
  const float* Ab = A + (size_t)(z / 4) * 65536;
  const float* Bb = B + (size_t)z * 65536;
  const float* rsb = rs + (size_t)(z / 4) * 256;
  float* Cb = C + (size_t)z * 65536;

  const int row0 = blockIdx.y * 128;
  const int col0 = blockIdx.x * 128;

  __shared__ short Ah[128][40];
  __shared__ short Bh[128][40];  // [n][k]
  __shared__ short Bl[128][40];

  const int tid = threadIdx.x;
  const int w = tid >> 6;
  const int wr = (w >> 1) * 64;
  const int wc = (w & 1) * 64;
  const int lane = tid & 63;
  const int fcol = lane & 15;
  const int kg = lane >> 4;

  const int am = tid >> 1;
  const int ak = (tid & 1) * 16;
  const int nq = (tid & 31) * 4;
  const int kb = (tid >> 5) * 4;

  float4v acc[4][4];
#pragma unroll
  for (int i = 0; i < 4; ++i)
#pragma unroll
    for (int j = 0; j < 4; ++j) acc[i][j] = (float4v)(0.0f);

  for (int k0 = 0; k0 < 256; k0 += 32) {
    float4 av[4];
#pragma unroll
    for (int q = 0; q < 4; ++q)
      av[q] = *(const float4*)(Ab + (size_t)(row0 + am) * 256 + k0 + ak + q * 4);
    float4 bv[4];
#pragma unroll
    for (int j = 0; j < 4; ++j)
      bv[j] = *(const float4*)(Bb + (size_t)(k0 + kb + j) * 256 + col0 + nq);

    __syncthreads();

    {
      short h[16];
#pragma unroll
      for (int q = 0; q < 4; ++q) {
        h[q * 4 + 0] = bf16_exact(av[q].x);
        h[q * 4 + 1] = bf16_exact(av[q].y);
        h[q * 4 + 2] = bf16_exact(av[q].z);
        h[q * 4 + 3] = bf16_exact(av[q].w);
      }
      *(short8v*)&Ah[am][ak] = *(short8v*)&h[0];
      *(short8v*)&Ah[am][ak + 8] = *(short8v*)&h[8];
    }
    {
      const float bm[4][4] = {{bv[0].x, bv[1].x, bv[2].x, bv[3].x},
                              {bv[0].y, bv[1].y, bv[2].y, bv[3].y},
                              {bv[0].z, bv[1].z, bv[2].z, bv[3].z},
                              {bv[0].w, bv[1].w, bv[2].w, bv[3].w}};
#pragma unroll
      for (int i = 0; i < 4; ++i) {
        short h[4], l[4];
#pragma unroll
        for (int j = 0; j < 4; ++j) split_bf16(bm[i][j], h[j], l[j]);
        *(short4v*)&Bh[nq + i][kb] = *(short4v*)&h[0];
        *(short4v*)&Bl[nq + i][kb] = *(short4v*)&l[0];
      }
    }
    __syncthreads();

    short8v afh[4], bfh[4], bfl[4];
#pragma unroll
    for (int im = 0; im < 4; ++im)
      afh[im] = *(const short8v*)&Ah[wr + im * 16 + fcol][kg * 8];
#pragma unroll
    for (int in = 0; in < 4; ++in) {
      bfh[in] = *(const short8v*)&Bh[wc + in * 16 + fcol][kg * 8];
      bfl[in] = *(const short8v*)&Bl[wc + in * 16 + fcol][kg * 8];
    }
#pragma unroll
    for (int im = 0; im < 4; ++im)
#pragma unroll
      for (int in = 0; in < 4; ++in) {
        acc[im][in] = __builtin_amdgcn_mfma_f32_16x16x32_bf16(
            afh[im], bfh[in], acc[im][in], 0, 0, 0);
        acc[im][in] = __builtin_amdgcn_mfma_f32_16x16x32_bf16(
            afh[im], bfl[in], acc[im][in], 0, 0, 0);
      }
  }

#pragma unroll
  for (int im = 0; im < 4; ++im) {
    const int rbase = row0 + wr + im * 16 + kg * 4;
    float rsv[4];
#pragma unroll
    for (int r = 0; r < 4; ++r) rsv[r] = rsb[rbase + r];
#pragma unroll
    for (int in = 0; in < 4; ++in) {
      const int col = col0 + wc + in * 16 + fcol;
#pragma unroll
      for (int r = 0; r < 4; ++r)
        Cb[(size_t)(rbase + r) * 256 + col] = acc[im][in][r] * rsv[r];
    }
  }
}

// ---------------------------------------------------------------------------
// K4: out = X @ Wl + bl. bf16x3 (3-term) MFMA.
// ---------------------------------------------------------------------------
__global__ __launch_bounds__(256) void gemm_mfma_kernel(
    const float* __restrict__ A, const float* __restrict__ B,
    const float* __restrict__ bias, float* __restrict__ C) {
  const int z = blockIdx.z;
  const float* Ab = A + (size_t)z * 65536;
  const float* Bb = B;  // shared Wl
  float* Cb = C + (size_t)z * 65536;

  const int row0 = blockIdx.y * 128;
  const int col0 = blockIdx.x * 128;

  __shared__ short Ah[128][40];
  __shared__ short Al[128][40];
  __shared__ short Bh[128][40];
  __shared__ short Bl[128][40];

  const int tid = threadIdx.x;
  const int w = tid >> 6;
  const int wr = (w >> 1) * 64;
  const int wc = (w & 1) * 64;
  const int lane = tid & 63;
  const int fcol = lane & 15;
  const int kg = lane >> 4;

  const int am = tid >> 1;
  const int ak = (tid & 1) * 16;
  const int nq = (tid & 31) * 4;
  const int kb = (tid >> 5) * 4;

  float4v acc[4][4];
#pragma unroll
  for (int i = 0; i < 4; ++i)
#pragma unroll
    for (int j = 0; j < 4; ++j) acc[i][j] = (float4v)(0.0f);

  for (int k0 = 0; k0 < 256; k0 += 32) {
    float4 av[4];
#pragma unroll
    for (int q = 0; q < 4; ++q)
      av[q] = *(const float4*)(Ab + (size_t)(row0 + am) * 256 + k0 + ak + q * 4);
    float4 bv[4];
#pragma unroll
    for (int j = 0; j < 4; ++j)
      bv[j] = *(const float4*)(Bb + (size_t)(k0 + kb + j) * 256 + col0 + nq);

    __syncthreads();

    {
      short h[16], l[16];
#pragma unroll
      for (int q = 0; q < 4; ++q) {
        split_bf16(av[q].x, h[q * 4 + 0], l[q * 4 + 0]);
        split_bf16(av[q].y, h[q * 4 + 1], l[q * 4 + 1]);
        split_bf16(av[q].z, h[q * 4 + 2], l[q * 4 + 2]);
        split_bf16(av[q].w, h[q * 4 + 3], l[q * 4 + 3]);
      }
      *(short8v*)&Ah[am][ak] = *(short8v*)&h[0];
      *(short8v*)&Ah[am][ak + 8] = *(short8v*)&h[8];
      *(short8v*)&Al[am][ak] = *(short8v*)&l[0];
      *(short8v*)&Al[am][ak + 8] = *(short8v*)&l[8];
    }
    {
      const float bm[4][4] = {{bv[0].x, bv[1].x, bv[2].x, bv[3].x},
                              {bv[0].y, bv[1].y, bv[2].y, bv[3].y},
                              {bv[0].z, bv[1].z, bv[2].z, bv[3].z},
                              {bv[0].w, bv[1].w, bv[2].w, bv[3].w}};
#pragma unroll
      for (int i = 0; i < 4; ++i) {
        short h[4], l[4];
#pragma unroll
        for (int j = 0; j < 4; ++j) split_bf16(bm[i][j], h[j], l[j]);
        *(short4v*)&Bh[nq + i][kb] = *(short4v*)&h[0];
        *(short4v*)&Bl[nq + i][kb] = *(short4v*)&l[0];
      }
    }
    __syncthreads();

    short8v afh[4], afl[4], bfh[4], bfl[4];
#pragma unroll
    for (int im = 0; im < 4; ++im) {
      afh[im] = *(const short8v*)&Ah[wr + im * 16 + fcol][kg * 8];
      afl[im] = *(const short8v*)&Al[wr + im * 16 + fcol][kg * 8];
    }
#pragma unroll
    for (int in = 0; in < 4; ++in) {
      bfh[in] = *(const short8v*)&Bh[wc + in * 16 + fcol][kg * 8];
      bfl[in] = *(const short8v*)&Bl[wc + in * 16 + fcol][kg * 8];
    }
#pragma unroll
    for (int im = 0; im < 4; ++im)
#pragma unroll
      for (int in = 0; in < 4; ++in) {
        acc[im][in] = __builtin_amdgcn_mfma_f32_16x16x32_bf16(
            afh[im], bfh[in], acc[im][in], 0, 0, 0);
        acc[im][in] = __builtin_amdgcn_mfma_f32_16x16x32_bf16(
            afh[im], bfl[in], acc[im][in], 0, 0, 0);
        acc[im][in] = __builtin_amdgcn_mfma_f32_16x16x32_bf16(
            afl[im], bfh[in], acc[im][in], 0, 0, 0);
      }
  }

#pragma unroll
  for (int in = 0; in < 4; ++in) {
    const int col = col0 + wc + in * 16 + fcol;
    const float bvx = bias[col];
#pragma unroll
    for (int im = 0; im < 4; ++im) {
      const int rbase = row0 + wr + im * 16 + kg * 4;
#pragma unroll
      for (int r = 0; r < 4; ++r)
        Cb[(size_t)(rbase + r) * 256 + col] = acc[im][in][r] + bvx;
    }
  }
}

extern "C" void kernel_launch(void* const* d_in, const int* in_sizes, int n_in,
                              void* d_out, int out_size, void* d_ws,
                              size_t ws_size, hipStream_t stream) {
  const float* features = (const float*)d_in[0];
  const float* fm       = (const float*)d_in[1];
  const float* W1 = (const float*)d_in[2];
  const float* b1 = (const float*)d_in[3];
  const float* W2 = (const float*)d_in[4];
  const float* b2 = (const float*)d_in[5];
  const float* W3 = (const float*)d_in[6];
  const float* b3 = (const float*)d_in[7];
  const float* Wl = (const float*)d_in[8];
  const float* bl = (const float*)d_in[9];
  float* out = (float*)d_out;

  // ws layout (44.0 MB):
  //   tbl      @ 0       .. 524KB
  //   rowscale @ 576KB   .. 608KB
  //   counter  @ 640KB   (4B), worklist follows (512KB)
  //   adj_bin  @ 2.0MB   .. 10.4MB  (f32)
  //   corr     @ 10.5MB  .. 18.9MB  (f32, dead after decide_fast)
  //   X        @ 10.5MB  .. 44.0MB  (f32, overwrites corr - safe)
  char* ws = (char*)d_ws;
  float* tbl        = (float*)ws;
  float* rowscale   = (float*)(ws + 576u * 1024u);
  uint32_t* counter = (uint32_t*)(ws + 640u * 1024u);
  uint32_t* worklist = counter + 16;
  float* adj_bin    = (float*)(ws + 2u * 1024u * 1024u);
  float* corr       = (float*)(ws + 10800u * 1024u);
  float* X          = (float*)(ws + 10800u * 1024u);

  build_table_kernel<<<dim3(513), 256, 0, stream>>>(W1, b1, W2, b2, W3, b3,
                                                    tbl);
  init_counter_kernel<<<dim3(1), 1, 0, stream>>>(counter);
  corr_mfma_kernel<<<dim3(2, 2, 32), 256, 0, stream>>>(fm, corr);
  decide_fast_kernel<<<dim3(8192), 256, 0, stream>>>(corr, tbl, adj_bin,
                                                     counter, worklist);
  decide_exact_kernel<<<dim3(2048), 256, 0, stream>>>(fm, counter, worklist,
                                                      W1, b1, W2, b2, W3, b3,
                                                      adj_bin);
  rowscale_kernel<<<dim3(2048), 256, 0, stream>>>(adj_bin, rowscale);
  // X[b,c] = rs * (adj_bin[b] @ F[b,c])   (X overwrites corr - consumed)
  gemm_binA_kernel<<<dim3(2, 2, 128), 256, 0, stream>>>(adj_bin, features,
                                                        rowscale, X);
  // out[b,c] = X[b,c] @ Wl + bl
  gemm_mfma_kernel<<<dim3(2, 2, 128), 256, 0, stream>>>(X, Wl, bl, out);
}

// Round 13
// 94.083 us; speedup vs baseline: 5.0062x; 1.0329x over previous
//
#include <hip/hip_runtime.h>
#include <stdint.h>

// ---------------------------------------------------------------------------
// B=32, C=4, S=256, L=256, Din=Dout=256
// Pipeline (6 dispatches):
//   K0 build_table: dphi table (131073 nodes, mlp32) + zero worklist counter
//   K1 corr_mfma:   corr[b] = fm[b] @ fm[b]^T, 4-term bf16-split MFMA, f32
//   K2 decide_fast: one block = one adj row; lerp+gumbel32 decision with
//                   dynamic guard thr = 4e-4 + slope*6e-4; adj as bf16;
//                   fused block rowsum -> rowsumF[row] (pend counts 0)
//   K3 decide_exact: ONE WAVE PER ITEM exact f64 (dot from fm + lane-parallel
//                   mlp64 + gumbel64, validated path); patches adj + rowsumF
//   K4 gemm_binA:   X[b,c] = (1/rowsumF) * (adj[b] @ F[b,c]); A staged as raw
//                   bf16 (exact), B split hi+lo (2-term)
//   K5 gemm_mfma:   out = X @ Wl + bl (bf16x3, 3-term)
// threefry partitionable (jax key 42): bits(i) = o0^o1 of tf2x32((0,42),(0,i))
// ---------------------------------------------------------------------------

#define TBL_INTERVALS 131072
#define TBL_MIN -128.0f
#define TBL_SCALE 512.0f
#define WL_CAP 131072u

typedef __attribute__((ext_vector_type(8))) short short8v;
typedef __attribute__((ext_vector_type(4))) short short4v;
typedef __attribute__((ext_vector_type(4))) float float4v;

__device__ __forceinline__ void threefry2x32(uint32_t x0, uint32_t x1,
                                             uint32_t& o0, uint32_t& o1) {
  const uint32_t ks0 = 0u;
  const uint32_t ks1 = 42u;
  const uint32_t ks2 = 0x1BD11BDAu ^ ks0 ^ ks1;
  const uint32_t ks[3] = {ks0, ks1, ks2};
  const uint32_t rot[2][4] = {{13u, 15u, 26u, 6u}, {17u, 29u, 16u, 24u}};
  x0 += ks0;
  x1 += ks1;
#pragma unroll
  for (int i = 0; i < 5; ++i) {
#pragma unroll
    for (int j = 0; j < 4; ++j) {
      const uint32_t r = rot[i & 1][j];
      x0 += x1;
      x1 = (x1 << r) | (x1 >> (32u - r));
      x1 ^= x0;
    }
    x0 += ks[(i + 1) % 3];
    x1 += ks[(i + 2) % 3] + (uint32_t)(i + 1);
  }
  o0 = x0;
  o1 = x1;
}

__device__ __forceinline__ float uniform_at(uint32_t j) {
  uint32_t o0, o1;
  threefry2x32(0u, j, o0, o1);
  const uint32_t bits = o0 ^ o1;
  uint32_t fb = (bits >> 9) | 0x3F800000u;
  float frac = __uint_as_float(fb) - 1.0f;
  return fmaxf(frac + 1e-10f, 1e-10f);
}

__device__ __forceinline__ double gumbel64_at(uint32_t j) {
  double t = -log((double)uniform_at(j));
  return -log(t);
}

__device__ __forceinline__ float gumbel32_at(uint32_t j) {
  float t = -logf(uniform_at(j));
  return -logf(t);
}

__device__ __forceinline__ double gelu_d(double x) {
  return 0.5 * x * (1.0 + erf(x * 0.70710678118654752440));
}

__device__ __forceinline__ float gelu_f(float x) {
  return 0.5f * x * (1.0f + erff(x * 0.70710678f));
}

__device__ __forceinline__ float mlp32(float corr, const float* __restrict__ W1,
                                       const float* __restrict__ b1,
                                       const float* __restrict__ W2,
                                       const float* __restrict__ b2,
                                       const float* __restrict__ W3,
                                       const float* __restrict__ b3) {
  float h1[16];
#pragma unroll
  for (int u = 0; u < 16; ++u) h1[u] = gelu_f(fmaf(corr, W1[u], b1[u]));
  float h2[8];
#pragma unroll
  for (int v = 0; v < 8; ++v) {
    float x = b2[v];
#pragma unroll
    for (int u = 0; u < 16; ++u) x = fmaf(h1[u], W2[u * 8 + v], x);
    h2[v] = gelu_f(x);
  }
  float l0 = b3[0], l1 = b3[1];
#pragma unroll
  for (int v = 0; v < 8; ++v) {
    l0 = fmaf(h2[v], W3[v * 2 + 0], l0);
    l1 = fmaf(h2[v], W3[v * 2 + 1], l1);
  }
  return l0 - l1;
}

// RNE f32 -> bf16 split
__device__ __forceinline__ void split_bf16(float x, short& h, short& l) {
  uint32_t u = __float_as_uint(x);
  uint32_t hr = (u + 0x7FFFu + ((u >> 16) & 1u)) >> 16;
  float hf = __uint_as_float(hr << 16);
  float lo = x - hf;
  uint32_t v = __float_as_uint(lo);
  uint32_t lr = (v + 0x7FFFu + ((v >> 16) & 1u)) >> 16;
  h = (short)hr;
  l = (short)lr;
}

// ---------------------------------------------------------------------------
// K0: build dphi table + zero worklist counter.
// ---------------------------------------------------------------------------
__global__ __launch_bounds__(256) void build_table_kernel(
    const float* __restrict__ W1, const float* __restrict__ b1,
    const float* __restrict__ W2, const float* __restrict__ b2,
    const float* __restrict__ W3, const float* __restrict__ b3,
    float* __restrict__ tbl, uint32_t* __restrict__ counter) {
  const int i = blockIdx.x * 256 + threadIdx.x;
  if (i == 0) counter[0] = 0u;
  if (i > TBL_INTERVALS) return;
  const float x = TBL_MIN + (float)i * (1.0f / TBL_SCALE);
  tbl[i] = mlp32(x, W1, b1, W2, b2, W3, b3);
}

// ---------------------------------------------------------------------------
// K1: corr[b] = fm[b] @ fm[b]^T via 4-term bf16-split MFMA, f32 output.
// 128x128 tile, BK=32, 4 waves x (64x64). grid (2,2,32).
// ---------------------------------------------------------------------------
__global__ __launch_bounds__(256) void corr_mfma_kernel(
    const float* __restrict__ fm, float* __restrict__ corr) {
  const int b = blockIdx.z;
  const float* base = fm + (size_t)b * 65536;
  const int row0 = blockIdx.y * 128;
  const int col0 = blockIdx.x * 128;

  __shared__ short Ah[128][40];
  __shared__ short Al[128][40];
  __shared__ short Bh[128][40];  // [n][k]
  __shared__ short Bl[128][40];

  const int tid = threadIdx.x;
  const int w = tid >> 6;
  const int wr = (w >> 1) * 64;
  const int wc = (w & 1) * 64;
  const int lane = tid & 63;
  const int fcol = lane & 15;
  const int kg = lane >> 4;

  const int am = tid >> 1;
  const int ak = (tid & 1) * 16;

  float4v acc[4][4];
#pragma unroll
  for (int i = 0; i < 4; ++i)
#pragma unroll
    for (int j = 0; j < 4; ++j) acc[i][j] = (float4v)(0.0f);

  for (int k0 = 0; k0 < 256; k0 += 32) {
    float4 av[4], bv[4];
#pragma unroll
    for (int q = 0; q < 4; ++q) {
      av[q] = *(const float4*)(base + (size_t)(row0 + am) * 256 + k0 + ak + q * 4);
      bv[q] = *(const float4*)(base + (size_t)(col0 + am) * 256 + k0 + ak + q * 4);
    }

    __syncthreads();

    {
      short h[16], l[16];
#pragma unroll
      for (int q = 0; q < 4; ++q) {
        split_bf16(av[q].x, h[q * 4 + 0], l[q * 4 + 0]);
        split_bf16(av[q].y, h[q * 4 + 1], l[q * 4 + 1]);
        split_bf16(av[q].z, h[q * 4 + 2], l[q * 4 + 2]);
        split_bf16(av[q].w, h[q * 4 + 3], l[q * 4 + 3]);
      }
      *(short8v*)&Ah[am][ak] = *(short8v*)&h[0];
      *(short8v*)&Ah[am][ak + 8] = *(short8v*)&h[8];
      *(short8v*)&Al[am][ak] = *(short8v*)&l[0];
      *(short8v*)&Al[am][ak + 8] = *(short8v*)&l[8];
#pragma unroll
      for (int q = 0; q < 4; ++q) {
        split_bf16(bv[q].x, h[q * 4 + 0], l[q * 4 + 0]);
        split_bf16(bv[q].y, h[q * 4 + 1], l[q * 4 + 1]);
        split_bf16(bv[q].z, h[q * 4 + 2], l[q * 4 + 2]);
        split_bf16(bv[q].w, h[q * 4 + 3], l[q * 4 + 3]);
      }
      *(short8v*)&Bh[am][ak] = *(short8v*)&h[0];
      *(short8v*)&Bh[am][ak + 8] = *(short8v*)&h[8];
      *(short8v*)&Bl[am][ak] = *(short8v*)&l[0];
      *(short8v*)&Bl[am][ak + 8] = *(short8v*)&l[8];
    }
    __syncthreads();

    short8v afh[4], afl[4], bfh[4], bfl[4];
#pragma unroll
    for (int im = 0; im < 4; ++im) {
      afh[im] = *(const short8v*)&Ah[wr + im * 16 + fcol][kg * 8];
      afl[im] = *(const short8v*)&Al[wr + im * 16 + fcol][kg * 8];
    }
#pragma unroll
    for (int in = 0; in < 4; ++in) {
      bfh[in] = *(const short8v*)&Bh[wc + in * 16 + fcol][kg * 8];
      bfl[in] = *(const short8v*)&Bl[wc + in * 16 + fcol][kg * 8];
    }
#pragma unroll
    for (int im = 0; im < 4; ++im)
#pragma unroll
      for (int in = 0; in < 4; ++in) {
        acc[im][in] = __builtin_amdgcn_mfma_f32_16x16x32_bf16(
            afh[im], bfh[in], acc[im][in], 0, 0, 0);
        acc[im][in] = __builtin_amdgcn_mfma_f32_16x16x32_bf16(
            afh[im], bfl[in], acc[im][in], 0, 0, 0);
        acc[im][in] = __builtin_amdgcn_mfma_f32_16x16x32_bf16(
            afl[im], bfh[in], acc[im][in], 0, 0, 0);
        acc[im][in] = __builtin_amdgcn_mfma_f32_16x16x32_bf16(
            afl[im], bfl[in], acc[im][in], 0, 0, 0);
      }
  }

  float* Cb = corr + (size_t)b * 65536;
#pragma unroll
  for (int in = 0; in < 4; ++in) {
    const int col = col0 + wc + in * 16 + fcol;
#pragma unroll
    for (int im = 0; im < 4; ++im) {
      const int rbase = row0 + wr + im * 16 + kg * 4;
#pragma unroll
      for (int r = 0; r < 4; ++r)
        Cb[(size_t)(rbase + r) * 256 + col] = acc[im][in][r];
    }
  }
}

// ---------------------------------------------------------------------------
// K2: decide_fast + fused rowsum. One block = one (b,s) row; one thread per
// element. Dynamic guard thr = 4e-4 + |d_tbl|*512*6e-4. adj as bf16 ushort.
// grid 8192 x 256.
// ---------------------------------------------------------------------------
__global__ __launch_bounds__(256) void decide_fast_kernel(
    const float* __restrict__ corr, const float* __restrict__ tbl,
    unsigned short* __restrict__ adj_bin, uint32_t* __restrict__ counter,
    uint32_t* __restrict__ worklist, float* __restrict__ rowsumF) {
  const uint32_t flat = blockIdx.x * 256u + threadIdx.x;  // < 2,097,152
  const int t = threadIdx.x;
  const int s = blockIdx.x & 255;

  float a = 1.0f;
  bool pend = false;
  if (t != s) {
    const float cf = corr[flat];
    if (fabsf(cf) >= 127.0f) {
      pend = true;
      a = 0.0f;
    } else {
      const float xf = (cf - TBL_MIN) * TBL_SCALE;
      const int i = (int)xf;
      const float fr = xf - (float)i;
      const float t0v = tbl[i];
      const float t1v = tbl[i + 1];
      const float dt = t1v - t0v;
      const float dphi = fmaf(fr, dt, t0v);

      const float g0 = gumbel32_at(2u * flat);
      const float g1 = gumbel32_at(2u * flat + 1u);
      const float d = dphi - (g1 - g0);
      const float thr = fmaf(fabsf(dt), 0.3072f, 4e-4f);
      if (fabsf(d) >= thr) {
        a = (d >= 0.0f) ? 1.0f : 0.0f;
      } else {
        pend = true;
        a = 0.0f;
      }
    }
  }
  if (pend) {
    const uint32_t idx = atomicAdd(counter, 1u);
    if (idx < WL_CAP) worklist[idx] = flat;
  }
  adj_bin[flat] = (a == 1.0f) ? (unsigned short)0x3F80u : (unsigned short)0u;

  // fused rowsum (pend counts 0; decide_exact patches via atomicAdd)
  float sum = a;
#pragma unroll
  for (int off = 32; off; off >>= 1) sum += __shfl_xor(sum, off);
  __shared__ float red[4];
  if ((threadIdx.x & 63) == 0) red[threadIdx.x >> 6] = sum;
  __syncthreads();
  if (threadIdx.x == 0)
    rowsumF[blockIdx.x] = red[0] + red[1] + red[2] + red[3];
}

// ---------------------------------------------------------------------------
// K3: exact f64 resolve, ONE WAVE PER ITEM (validated round-11/12 path).
// Patches adj (bf16) and rowsumF (atomicAdd +1 for resolved ones).
// grid 2048 x 256.
// ---------------------------------------------------------------------------
__global__ __launch_bounds__(256) void decide_exact_kernel(
    const float* __restrict__ fm, const uint32_t* __restrict__ counter,
    const uint32_t* __restrict__ worklist,
    const float* __restrict__ W1, const float* __restrict__ b1,
    const float* __restrict__ W2, const float* __restrict__ b2,
    const float* __restrict__ W3, const float* __restrict__ b3,
    unsigned short* __restrict__ adj_bin, float* __restrict__ rowsumF) {
  const uint32_t n = min(counter[0], WL_CAP);
  const uint32_t waveId = (blockIdx.x * 256u + threadIdx.x) >> 6;
  const uint32_t nWaves = (gridDim.x * 256u) >> 6;
  const int lane = threadIdx.x & 63;

  for (uint32_t it = waveId; it < n; it += nWaves) {
    const uint32_t flat = worklist[it];
    const uint32_t bb = flat >> 16;
    const uint32_t ss = (flat >> 8) & 255u;
    const uint32_t tt = flat & 255u;

    // exact f64 dot: lane k-slices, coalesced; butterfly reduce (fixed order)
    const float* S = fm + ((size_t)bb * 256 + ss) * 256;
    const float* T = fm + ((size_t)bb * 256 + tt) * 256;
    double p = 0.0;
#pragma unroll
    for (int q = 0; q < 4; ++q) {
      const int k = lane + q * 64;
      p += (double)S[k] * (double)T[k];
    }
#pragma unroll
    for (int off = 32; off; off >>= 1) p += __shfl_xor(p, off);
    const double acc = p;

    // gumbel chain (overlaps MLP chain): lane&1 selects G0/G1
    const double ga = gumbel64_at(2u * flat + (uint32_t)(lane & 1));

    // h1 on lanes (u = lane & 15)
    const int u = lane & 15;
    const double h1 = gelu_d(acc * (double)W1[u] + (double)b1[u]);

    // h2 on lanes (v = lane & 7), same sequential u-order as mlp64
    const int v = lane & 7;
    double sv = (double)b2[v];
#pragma unroll
    for (int uu = 0; uu < 16; ++uu) {
      const double h1u = __shfl(h1, uu);
      sv += h1u * (double)W2[uu * 8 + v];
    }
    const double h2 = gelu_d(sv);

    // l0/l1, same sequential v-order
    double l0 = (double)b3[0], l1 = (double)b3[1];
#pragma unroll
    for (int vv = 0; vv < 8; ++vv) {
      const double h2v = __shfl(h2, vv);
      l0 += h2v * (double)W3[vv * 2 + 0];
      l1 += h2v * (double)W3[vv * 2 + 1];
    }

    const double G0 = __shfl(ga, 0);
    const double G1 = __shfl(ga, 1);
    if (lane == 0) {
      const bool one = (l0 + G0 >= l1 + G1);
      adj_bin[flat] = one ? (unsigned short)0x3F80u : (unsigned short)0u;
      if (one) atomicAdd(&rowsumF[flat >> 8], 1.0f);
    }
  }
}

// ---------------------------------------------------------------------------
// K4: X[b,c] = (1/rowsumF) * (adj[b] @ F[b,c]). A raw bf16 (exact binary),
// B split hi+lo (2-term) -> 32 MFMA / K-step.
// ---------------------------------------------------------------------------
__global__ __launch_bounds__(256) void gemm_binA_kernel(
    const unsigned short* __restrict__ A, const float* __restrict__ B,
    const float* __restrict__ rowsumF, float* __restrict__ C) {
  const int z = blockIdx.z;
  const unsigned short* Ab = A + (size_t)(z / 4) * 65536;
  const float* Bb = B + (size_t)z * 65536;
  const float* rsb = rowsumF + (size_t)(z / 4) * 256;
  float* Cb = C + (size_t)z * 65536;

  const int row0 = blockIdx.y * 128;
  const int col0 = blockIdx.x * 128;

  __shared__ short Ah[128][40];
  __shared__ short Bh[128][40];  // [n][k]
  __shared__ short Bl[128][40];

  const int tid = threadIdx.x;
  const int w = tid >> 6;
  const int wr = (w >> 1) * 64;
  const int wc = (w & 1) * 64;
  const int lane = tid & 63;
  const int fcol = lane & 15;
  const int kg = lane >> 4;

  const int am = tid >> 1;
  const int ak = (tid & 1) * 16;
  const int nq = (tid & 31) * 4;
  const int kb = (tid >> 5) * 4;

  float4v acc[4][4];
#pragma unroll
  for (int i = 0; i < 4; ++i)
#pragma unroll
    for (int j = 0; j < 4; ++j) acc[i][j] = (float4v)(0.0f);

  for (int k0 = 0; k0 < 256; k0 += 32) {
    short8v a0 = *(const short8v*)(Ab + (size_t)(row0 + am) * 256 + k0 + ak);
    short8v a1 = *(const short8v*)(Ab + (size_t)(row0 + am) * 256 + k0 + ak + 8);
    float4 bv[4];
#pragma unroll
    for (int j = 0; j < 4; ++j)
      bv[j] = *(const float4*)(Bb + (size_t)(k0 + kb + j) * 256 + col0 + nq);

    __syncthreads();

    *(short8v*)&Ah[am][ak] = a0;
    *(short8v*)&Ah[am][ak + 8] = a1;
    {
      const float bm[4][4] = {{bv[0].x, bv[1].x, bv[2].x, bv[3].x},
                              {bv[0].y, bv[1].y, bv[2].y, bv[3].y},
                              {bv[0].z, bv[1].z, bv[2].z, bv[3].z},
                              {bv[0].w, bv[1].w, bv[2].w, bv[3].w}};
#pragma unroll
      for (int i = 0; i < 4; ++i) {
        short h[4], l[4];
#pragma unroll
        for (int j = 0; j < 4; ++j) split_bf16(bm[i][j], h[j], l[j]);
        *(short4v*)&Bh[nq + i][kb] = *(short4v*)&h[0];
        *(short4v*)&Bl[nq + i][kb] = *(short4v*)&l[0];
      }
    }
    __syncthreads();

    short8v afh[4], bfh[4], bfl[4];
#pragma unroll
    for (int im = 0; im < 4; ++im)
      afh[im] = *(const short8v*)&Ah[wr + im * 16 + fcol][kg * 8];
#pragma unroll
    for (int in = 0; in < 4; ++in) {
      bfh[in] = *(const short8v*)&Bh[wc + in * 16 + fcol][kg * 8];
      bfl[in] = *(const short8v*)&Bl[wc + in * 16 + fcol][kg * 8];
    }
#pragma unroll
    for (int im = 0; im < 4; ++im)
#pragma unroll
      for (int in = 0; in < 4; ++in) {
        acc[im][in] = __builtin_amdgcn_mfma_f32_16x16x32_bf16(
            afh[im], bfh[in], acc[im][in], 0, 0, 0);
        acc[im][in] = __builtin_amdgcn_mfma_f32_16x16x32_bf16(
            afh[im], bfl[in], acc[im][in], 0, 0, 0);
      }
  }

#pragma unroll
  for (int im = 0; im < 4; ++im) {
    const int rbase = row0 + wr + im * 16 + kg * 4;
    float rsv[4];
#pragma unroll
    for (int r = 0; r < 4; ++r) rsv[r] = 1.0f / rsb[rbase + r];
#pragma unroll
    for (int in = 0; in < 4; ++in) {
      const int col = col0 + wc + in * 16 + fcol;
#pragma unroll
      for (int r = 0; r < 4; ++r)
        Cb[(size_t)(rbase + r) * 256 + col] = acc[im][in][r] * rsv[r];
    }
  }
}

// ---------------------------------------------------------------------------
// K5: out = X @ Wl + bl. bf16x3 (3-term) MFMA.
// ---------------------------------------------------------------------------
__global__ __launch_bounds__(256) void gemm_mfma_kernel(
    const float* __restrict__ A, const float* __restrict__ B,
    const float* __restrict__ bias, float* __restrict__ C) {
  const int z = blockIdx.z;
  const float* Ab = A + (size_t)z * 65536;
  const float* Bb = B;  // shared Wl
  float* Cb = C + (size_t)z * 65536;

  const int row0 = blockIdx.y * 128;
  const int col0 = blockIdx.x * 128;

  __shared__ short Ah[128][40];
  __shared__ short Al[128][40];
  __shared__ short Bh[128][40];
  __shared__ short Bl[128][40];

  const int tid = threadIdx.x;
  const int w = tid >> 6;
  const int wr = (w >> 1) * 64;
  const int wc = (w & 1) * 64;
  const int lane = tid & 63;
  const int fcol = lane & 15;
  const int kg = lane >> 4;

  const int am = tid >> 1;
  const int ak = (tid & 1) * 16;
  const int nq = (tid & 31) * 4;
  const int kb = (tid >> 5) * 4;

  float4v acc[4][4];
#pragma unroll
  for (int i = 0; i < 4; ++i)
#pragma unroll
    for (int j = 0; j < 4; ++j) acc[i][j] = (float4v)(0.0f);

  for (int k0 = 0; k0 < 256; k0 += 32) {
    float4 av[4];
#pragma unroll
    for (int q = 0; q < 4; ++q)
      av[q] = *(const float4*)(Ab + (size_t)(row0 + am) * 256 + k0 + ak + q * 4);
    float4 bv[4];
#pragma unroll
    for (int j = 0; j < 4; ++j)
      bv[j] = *(const float4*)(Bb + (size_t)(k0 + kb + j) * 256 + col0 + nq);

    __syncthreads();

    {
      short h[16], l[16];
#pragma unroll
      for (int q = 0; q < 4; ++q) {
        split_bf16(av[q].x, h[q * 4 + 0], l[q * 4 + 0]);
        split_bf16(av[q].y, h[q * 4 + 1], l[q * 4 + 1]);
        split_bf16(av[q].z, h[q * 4 + 2], l[q * 4 + 2]);
        split_bf16(av[q].w, h[q * 4 + 3], l[q * 4 + 3]);
      }
      *(short8v*)&Ah[am][ak] = *(short8v*)&h[0];
      *(short8v*)&Ah[am][ak + 8] = *(short8v*)&h[8];
      *(short8v*)&Al[am][ak] = *(short8v*)&l[0];
      *(short8v*)&Al[am][ak + 8] = *(short8v*)&l[8];
    }
    {
      const float bm[4][4] = {{bv[0].x, bv[1].x, bv[2].x, bv[3].x},
                              {bv[0].y, bv[1].y, bv[2].y, bv[3].y},
                              {bv[0].z, bv[1].z, bv[2].z, bv[3].z},
                              {bv[0].w, bv[1].w, bv[2].w, bv[3].w}};
#pragma unroll
      for (int i = 0; i < 4; ++i) {
        short h[4], l[4];
#pragma unroll
        for (int j = 0; j < 4; ++j) split_bf16(bm[i][j], h[j], l[j]);
        *(short4v*)&Bh[nq + i][kb] = *(short4v*)&h[0];
        *(short4v*)&Bl[nq + i][kb] = *(short4v*)&l[0];
      }
    }
    __syncthreads();

    short8v afh[4], afl[4], bfh[4], bfl[4];
#pragma unroll
    for (int im = 0; im < 4; ++im) {
      afh[im] = *(const short8v*)&Ah[wr + im * 16 + fcol][kg * 8];
      afl[im] = *(const short8v*)&Al[wr + im * 16 + fcol][kg * 8];
    }
#pragma unroll
    for (int in = 0; in < 4; ++in) {
      bfh[in] = *(const short8v*)&Bh[wc + in * 16 + fcol][kg * 8];
      bfl[in] = *(const short8v*)&Bl[wc + in * 16 + fcol][kg * 8];
    }
#pragma unroll
    for (int im = 0; im < 4; ++im)
#pragma unroll
      for (int in = 0; in < 4; ++in) {
        acc[im][in] = __builtin_amdgcn_mfma_f32_16x16x32_bf16(
            afh[im], bfh[in], acc[im][in], 0, 0, 0);
        acc[im][in] = __builtin_amdgcn_mfma_f32_16x16x32_bf16(
            afh[im], bfl[in], acc[im][in], 0, 0, 0);
        acc[im][in] = __builtin_amdgcn_mfma_f32_16x16x32_bf16(
            afl[im], bfh[in], acc[im][in], 0, 0, 0);
      }
  }

#pragma unroll
  for (int in = 0; in < 4; ++in) {
    const int col = col0 + wc + in * 16 + fcol;
    const float bvx = bias[col];
#pragma unroll
    for (int im = 0; im < 4; ++im) {
      const int rbase = row0 + wr + im * 16 + kg * 4;
#pragma unroll
      for (int r = 0; r < 4; ++r)
        Cb[(size_t)(rbase + r) * 256 + col] = acc[im][in][r] + bvx;
    }
  }
}

extern "C" void kernel_launch(void* const* d_in, const int* in_sizes, int n_in,
                              void* d_out, int out_size, void* d_ws,
                              size_t ws_size, hipStream_t stream) {
  const float* features = (const float*)d_in[0];
  const float* fm       = (const float*)d_in[1];
  const float* W1 = (const float*)d_in[2];
  const float* b1 = (const float*)d_in[3];
  const float* W2 = (const float*)d_in[4];
  const float* b2 = (const float*)d_in[5];
  const float* W3 = (const float*)d_in[6];
  const float* b3 = (const float*)d_in[7];
  const float* Wl = (const float*)d_in[8];
  const float* bl = (const float*)d_in[9];
  float* out = (float*)d_out;

  // ws layout (44.0 MB):
  //   tbl      @ 0       .. 524KB
  //   rowsumF  @ 576KB   .. 608KB   (8192 f32)
  //   counter  @ 640KB   (4B), worklist follows (512KB)
  //   adj_bin  @ 2.0MB   .. 6.2MB   (bf16 ushort, 4.2MB)
  //   corr     @ 10.5MB  .. 18.9MB  (f32, dead after decide_fast)
  //   X        @ 10.5MB  .. 44.0MB  (f32, overwrites corr - safe)
  char* ws = (char*)d_ws;
  float* tbl          = (float*)ws;
  float* rowsumF      = (float*)(ws + 576u * 1024u);
  uint32_t* counter   = (uint32_t*)(ws + 640u * 1024u);
  uint32_t* worklist  = counter + 16;
  unsigned short* adj = (unsigned short*)(ws + 2u * 1024u * 1024u);
  float* corr         = (float*)(ws + 10800u * 1024u);
  float* X            = (float*)(ws + 10800u * 1024u);

  build_table_kernel<<<dim3(513), 256, 0, stream>>>(W1, b1, W2, b2, W3, b3,
                                                    tbl, counter);
  corr_mfma_kernel<<<dim3(2, 2, 32), 256, 0, stream>>>(fm, corr);
  decide_fast_kernel<<<dim3(8192), 256, 0, stream>>>(corr, tbl, adj, counter,
                                                     worklist, rowsumF);
  decide_exact_kernel<<<dim3(2048), 256, 0, stream>>>(fm, counter, worklist,
                                                      W1, b1, W2, b2, W3, b3,
                                                      adj, rowsumF);
  // X[b,c] = (1/rowsum) * (adj[b] @ F[b,c])   (X overwrites corr - consumed)
  gemm_binA_kernel<<<dim3(2, 2, 128), 256, 0, stream>>>(adj, features,
                                                        rowsumF, X);
  // out[b,c] = X[b,c] @ Wl + bl
  gemm_mfma_kernel<<<dim3(2, 2, 128), 256, 0, stream>>>(X, Wl, bl, out);
}